// Round 15
// baseline (229.766 us; speedup 1.0000x reference)
//
#include <hip/hip_runtime.h>
#include <hip/hip_fp16.h>

#define N_NODES 50000
#define N_EDGES 800000
#define NEG_SLOPE 0.2f
#define NBKT 196            // ceil(50000/256) buckets of 256 nodes
#define EBLK 200            // edge blocks
#define CHUNK 4000          // edges per block (EBLK*CHUNK == N_EDGES)
#define GEMM_BLOCKS 782     // ceil(50000/64)

__device__ __forceinline__ float leaky(float x) { return x >= 0.f ? x : NEG_SLOPE * x; }
__device__ __forceinline__ float readlane_f(float v, int i) {
    return __uint_as_float(__builtin_amdgcn_readlane(__float_as_uint(v), i));
}
// order-preserving float<->uint mapping for atomicMax on mixed-sign floats
__device__ __forceinline__ unsigned enc_f(float f) {
    unsigned u = __float_as_uint(f);
    return (int)u < 0 ? ~u : (u | 0x80000000u);
}
__device__ __forceinline__ float dec_f(unsigned e) {
    return __uint_as_float((int)e < 0 ? (e & 0x7FFFFFFFu) : ~e);
}

// NL-deep pipelined gather salvo (NL >= wave's deg; fillers carry w=0)
template <int NL>
__device__ __forceinline__ float salvo(int mysrc, float w64,
                                       const __half* __restrict__ h,
                                       int lane, float acc)
{
    float hv[NL];
    #pragma unroll
    for (int j = 0; j < NL; ++j) {
        int s = __builtin_amdgcn_readlane(mysrc, j);
        hv[j] = __half2float(h[(size_t)s * 64 + lane]);
    }
    #pragma unroll
    for (int j = 0; j < NL; ++j)
        acc += readlane_f(w64, j) * hv[j];
    return acc;
}

// ---------------------------------------------------------------------------
// GEMM body: h(fp16) = x@W, s_src/s_dst (f32). 64x64 tile, BK=32, 4x4/thread.
// Block s_src max -> bmax[blockIdx] (layer 1; reduced in p23).
// ---------------------------------------------------------------------------
template <int K>
__device__ __forceinline__ void gemm_body(
    const float* __restrict__ x, const float* __restrict__ W,
    const float* __restrict__ a_src, const float* __restrict__ a_dst,
    __half* __restrict__ h, float* __restrict__ s_src, float* __restrict__ s_dst,
    float* __restrict__ bmax, int n)
{
    constexpr int BK = 32;
    __shared__ float Wl[BK][64];
    __shared__ float xt[BK][68];
    __shared__ float asl[64], adl[64];
    __shared__ float wm[4];

    int tid = threadIdx.x;
    if (tid < 64) { asl[tid] = a_src[tid]; adl[tid] = a_dst[tid]; }
    int tx = tid & 15, ty = tid >> 4;
    int row0 = blockIdx.x * 64;

    float acc[4][4] = {};

    for (int k0 = 0; k0 < K; k0 += BK) {
        __syncthreads();
        {
            const float4* Wg = (const float4*)&W[(size_t)k0 * 64];
            float4* Ws = (float4*)&Wl[0][0];
            Ws[tid]       = Wg[tid];
            Ws[tid + 256] = Wg[tid + 256];
        }
        #pragma unroll
        for (int it = 0; it < 2; ++it) {
            int idx = tid + it * 256;
            int r = idx >> 3, kq = idx & 7;
            int grow = row0 + r;
            float4 v = (grow < n) ? *(const float4*)&x[(size_t)grow * K + k0 + kq * 4]
                                  : make_float4(0.f, 0.f, 0.f, 0.f);
            xt[kq * 4 + 0][r] = v.x;
            xt[kq * 4 + 1][r] = v.y;
            xt[kq * 4 + 2][r] = v.z;
            xt[kq * 4 + 3][r] = v.w;
        }
        __syncthreads();

        #pragma unroll
        for (int kk = 0; kk < BK; ++kk) {
            float4 wv = *(const float4*)&Wl[kk][tx * 4];
            float4 xv = *(const float4*)&xt[kk][ty * 4];
            acc[0][0] += xv.x * wv.x; acc[0][1] += xv.x * wv.y; acc[0][2] += xv.x * wv.z; acc[0][3] += xv.x * wv.w;
            acc[1][0] += xv.y * wv.x; acc[1][1] += xv.y * wv.y; acc[1][2] += xv.y * wv.z; acc[1][3] += xv.y * wv.w;
            acc[2][0] += xv.z * wv.x; acc[2][1] += xv.z * wv.y; acc[2][2] += xv.z * wv.z; acc[2][3] += xv.z * wv.w;
            acc[3][0] += xv.w * wv.x; acc[3][1] += xv.w * wv.y; acc[3][2] += xv.w * wv.z; acc[3][3] += xv.w * wv.w;
        }
    }

    float wmax = -INFINITY;
    #pragma unroll
    for (int i = 0; i < 4; ++i) {
        int grow = row0 + ty * 4 + i;
        if (grow < n) {
            __half2 p0 = __floats2half2_rn(acc[i][0], acc[i][1]);
            __half2 p1 = __floats2half2_rn(acc[i][2], acc[i][3]);
            uint2 pk = make_uint2(*(unsigned*)&p0, *(unsigned*)&p1);
            *(uint2*)&h[(size_t)grow * 64 + tx * 4] = pk;
        }
        float s1 = acc[i][0] * asl[tx*4+0] + acc[i][1] * asl[tx*4+1]
                 + acc[i][2] * asl[tx*4+2] + acc[i][3] * asl[tx*4+3];
        float s2 = acc[i][0] * adl[tx*4+0] + acc[i][1] * adl[tx*4+1]
                 + acc[i][2] * adl[tx*4+2] + acc[i][3] * adl[tx*4+3];
        #pragma unroll
        for (int m = 1; m < 16; m <<= 1) {
            s1 += __shfl_xor(s1, m, 64);
            s2 += __shfl_xor(s2, m, 64);
        }
        if (grow < n) wmax = fmaxf(wmax, s1);
        if (tx == 0 && grow < n) { s_src[grow] = s1; s_dst[grow] = s2; }
    }
    wmax = fmaxf(wmax, __shfl_xor(wmax, 16, 64));
    wmax = fmaxf(wmax, __shfl_xor(wmax, 32, 64));
    if ((tid & 63) == 0) wm[tid >> 6] = wmax;
    __syncthreads();
    if (tid == 0)
        bmax[blockIdx.x] = fmaxf(fmaxf(wm[0], wm[1]), fmaxf(wm[2], wm[3]));
}

// K1: gemm1 (blocks 0..781) || CSR P1 histogram (blocks 782..981).
template <int K>
__global__ __launch_bounds__(256) void fused_gemm_p1(
    const float* __restrict__ x, const float* __restrict__ W,
    const float* __restrict__ a_src, const float* __restrict__ a_dst,
    __half* __restrict__ h, float* __restrict__ s_src, float* __restrict__ s_dst,
    float* __restrict__ bmax,
    const int* __restrict__ dst_, int* __restrict__ cnt, int n)
{
    if (blockIdx.x >= GEMM_BLOCKS) {
        __shared__ int bins[NBKT];
        int tid = threadIdx.x, b = blockIdx.x - GEMM_BLOCKS;
        if (tid < NBKT) bins[tid] = 0;
        __syncthreads();
        int e0 = b * CHUNK;
        for (int e = e0 + tid; e < e0 + CHUNK; e += 256)
            atomicAdd(&bins[dst_[e] >> 8], 1);
        __syncthreads();
        if (tid < NBKT) cnt[b * NBKT + tid] = bins[tid];
        return;
    }
    gemm_body<K>(x, W, a_src, a_dst, h, s_src, s_dst, bmax, n);
}

// ---------------------------------------------------------------------------
// K2: P2+P3 fused, barrier-free (R14-identical). Block 0 also writes btot,
// reduces bmax -> gmaxu[0], zeroes gmaxu[1].
// ---------------------------------------------------------------------------
__global__ __launch_bounds__(256) void p23_fused(
    const int* __restrict__ cnt, int* __restrict__ btot,
    const float* __restrict__ bmax, unsigned* __restrict__ gmaxu,
    const int* __restrict__ src, const int* __restrict__ dst,
    unsigned* __restrict__ bkted)
{
    __shared__ int tmp[256];
    __shared__ int boffL[NBKT];
    __shared__ float fm[4];
    int b = blockIdx.x, tid = threadIdx.x;

    int total = 0, myoff = 0;
    if (tid < NBKT) {
        for (int bp = 0; bp < EBLK; ++bp) {
            int v = cnt[bp * NBKT + tid];
            total += v;
            if (bp < b) myoff += v;
        }
    }
    tmp[tid] = (tid < NBKT) ? total : 0;
    __syncthreads();
    for (int off = 1; off < 256; off <<= 1) {
        int a = (tid >= off) ? tmp[tid - off] : 0;
        __syncthreads();
        tmp[tid] += a;
        __syncthreads();
    }
    if (tid < NBKT) {
        int base = tmp[tid] - total;
        boffL[tid] = base + myoff;
        if (b == 0) btot[tid] = total;
    }
    __syncthreads();

    int e0 = b * CHUNK;
    for (int e = e0 + tid; e < e0 + CHUNK; e += 256) {
        int d = dst[e], s = src[e];
        int pos = atomicAdd(&boffL[d >> 8], 1);
        bkted[pos] = ((unsigned)(d & 255) << 16) | (unsigned)s;
    }

    if (b == 0) {
        float m = -INFINITY;
        for (int i = tid; i < GEMM_BLOCKS; i += 256) m = fmaxf(m, bmax[i]);
        #pragma unroll
        for (int off = 32; off; off >>= 1) m = fmaxf(m, __shfl_xor(m, off, 64));
        if ((tid & 63) == 0) fm[tid >> 6] = m;
        __syncthreads();
        if (tid == 0) {
            gmaxu[0] = enc_f(fmaxf(fmaxf(fm[0], fm[1]), fmaxf(fm[2], fm[3])));
            gmaxu[1] = 0;
        }
    }
}

// P4: one block per bucket; per-node count/scan/scatter in LDS (R14-identical).
__global__ __launch_bounds__(256) void p4_csr(
    const unsigned* __restrict__ bkted, const int* __restrict__ btot,
    int* __restrict__ row_off, int* __restrict__ csr_src)
{
    __shared__ int tmp[256];
    __shared__ int cur[256];
    __shared__ int s_beg, s_end;
    int j = blockIdx.x, tid = threadIdx.x;
    int v = (tid < NBKT) ? btot[tid] : 0;
    tmp[tid] = v; __syncthreads();
    for (int off = 1; off < 256; off <<= 1) {
        int a = (tid >= off) ? tmp[tid - off] : 0;
        __syncthreads();
        tmp[tid] += a;
        __syncthreads();
    }
    if (tid == j) { s_beg = tmp[tid] - v; s_end = tmp[tid]; }
    cur[tid] = 0;
    __syncthreads();
    int beg = s_beg, end = s_end;

    for (int e = beg + tid; e < end; e += 256)
        atomicAdd(&cur[bkted[e] >> 16], 1);
    __syncthreads();
    int c = cur[tid];
    tmp[tid] = c; __syncthreads();
    for (int off = 1; off < 256; off <<= 1) {
        int a = (tid >= off) ? tmp[tid - off] : 0;
        __syncthreads();
        tmp[tid] += a;
        __syncthreads();
    }
    int offx = tmp[tid] - c;
    int node = j * 256 + tid;
    if (node < N_NODES) row_off[node] = beg + offx;
    if (node == 0) row_off[N_NODES] = N_EDGES;
    __syncthreads();
    cur[tid] = offx;
    __syncthreads();
    for (int e = beg + tid; e < end; e += 256) {
        unsigned u = bkted[e];
        int pos = beg + atomicAdd(&cur[u >> 16], 1);
        csr_src[pos] = (int)(u & 0xFFFFu);
    }
}

// ---------------------------------------------------------------------------
// Shared aggregation: returns per-lane v = (softmax-weighted sum)/den + bias
// (lane = dim). Tiered salvo: 16 / 32 / generic.
// ---------------------------------------------------------------------------
__device__ __forceinline__ float aggregate_row(
    int row, int lane,
    const int* __restrict__ row_off, const int* __restrict__ csr_src,
    const float* __restrict__ s_src, const float* __restrict__ s_dst,
    const __half* __restrict__ h, const float* __restrict__ bvec,
    float m_base)
{
    int beg = row_off[row], end = row_off[row + 1];
    int deg = end - beg;
    float sd = s_dst[row];
    float m = leaky(m_base + sd);               // uniform upper bound, cancels
    float hself = __half2float(h[(size_t)row * 64 + lane]);
    float wself = __expf(leaky(s_src[row] + sd) - m);

    int   mysrc   = row;                        // filler: hot self row, w=0
    float mylogit = -INFINITY;
    if (lane < deg) {
        mysrc = csr_src[beg + lane];
        mylogit = leaky(s_src[mysrc] + sd);
    }
    float w64 = __expf(mylogit - m);
    float den = w64;
    #pragma unroll
    for (int off = 32; off; off >>= 1)
        den += __shfl_xor(den, off, 64);
    den += wself;

    float acc = wself * hself;

    if (deg <= 16) {
        acc = salvo<16>(mysrc, w64, h, lane, acc);
    } else if (deg <= 32) {
        acc = salvo<32>(mysrc, w64, h, lane, acc);
    } else {
        int d0 = deg < 64 ? deg : 64;
        int nb = (d0 + 15) & ~15;
        for (int i = 0; i < nb; i += 16) {
            float hv[16];
            #pragma unroll
            for (int j = 0; j < 16; ++j) {
                int s = __builtin_amdgcn_readlane(mysrc, i + j);
                hv[j] = __half2float(h[(size_t)s * 64 + lane]);
            }
            #pragma unroll
            for (int j = 0; j < 16; ++j)
                acc += readlane_f(w64, i + j) * hv[j];
        }
        for (int e = beg + 64; e < end; ++e) {  // deg > 64 tail
            int s = csr_src[e];
            float w = __expf(leaky(s_src[s] + sd) - m);
            den += w;
            acc += w * __half2float(h[(size_t)s * 64 + lane]);
        }
    }
    return acc / den + bvec[lane];
}

// ---------------------------------------------------------------------------
// K4: layer-1 aggregation FUSED with gemm2. Per wave: aggregate -> v (lane =
// dim) -> ReLU -> h2 row = v @ W2 (W2 staged in LDS; readlane broadcasts) ->
// h2 fp16 + s2 scores + block atomicMax gmax2. Layer-1 out never hits global.
// ---------------------------------------------------------------------------
__global__ __launch_bounds__(256) void node1_gemm2_kernel(
    const int* __restrict__ row_off, const int* __restrict__ csr_src,
    const float* __restrict__ s_src, const float* __restrict__ s_dst,
    const __half* __restrict__ h, const float* __restrict__ b1,
    const float* __restrict__ W2,
    const float* __restrict__ a2s, const float* __restrict__ a2d,
    const unsigned* __restrict__ gmax1_enc, unsigned* __restrict__ gmax2_enc,
    __half* __restrict__ h2, float* __restrict__ s_src2, float* __restrict__ s_dst2,
    int n)
{
    __shared__ float W2l[64][64];
    __shared__ float b1l[64], a2sl[64], a2dl[64];
    __shared__ float wm[4];

    int tid = threadIdx.x;
    // stage W2 (16 KB) + vectors cooperatively
    {
        const float4* Wg = (const float4*)W2;
        float4* Ws = (float4*)&W2l[0][0];
        #pragma unroll
        for (int it = 0; it < 4; ++it)
            Ws[tid + it * 256] = Wg[tid + it * 256];
        if (tid < 64) { b1l[tid] = b1[tid]; a2sl[tid] = a2s[tid]; a2dl[tid] = a2d[tid]; }
    }
    __syncthreads();

    int row = blockIdx.x * 4 + (tid >> 6);
    int lane = tid & 63;
    float m_base = dec_f(*gmax1_enc);

    // layer-1 aggregation + bias + ReLU (v: lane = dim)
    float v = 0.f;
    if (row < n) {
        v = aggregate_row(row, lane, row_off, csr_src, s_src, s_dst, h, b1l, m_base);
        v = fmaxf(v, 0.f);
    }

    // gemm2: acc2[lane] = sum_k v_k * W2[k][lane]
    float acc2 = 0.f;
    #pragma unroll 8
    for (int k = 0; k < 64; ++k) {
        float vk = readlane_f(v, k);
        acc2 += vk * W2l[k][lane];
    }

    float s1 = acc2 * a2sl[lane];
    float s2 = acc2 * a2dl[lane];
    #pragma unroll
    for (int off = 1; off < 64; off <<= 1) {
        s1 += __shfl_xor(s1, off, 64);
        s2 += __shfl_xor(s2, off, 64);
    }

    if (row < n) {
        h2[(size_t)row * 64 + lane] = __float2half(acc2);
        if (lane == 0) { s_src2[row] = s1; s_dst2[row] = s2; }
    }

    // block max of s1 -> one atomicMax per block
    float wmax = (row < n) ? s1 : -INFINITY;
    if ((tid & 63) == 0) wm[tid >> 6] = wmax;
    __syncthreads();
    if (tid == 0) {
        float bm = fmaxf(fmaxf(wm[0], wm[1]), fmaxf(wm[2], wm[3]));
        atomicMax(gmax2_enc, enc_f(bm));
    }
}

// ---------------------------------------------------------------------------
// K5: layer-2 aggregation (final). Writes d_out.
// ---------------------------------------------------------------------------
__global__ __launch_bounds__(256) void gat_node_kernel(
    const int* __restrict__ row_off, const int* __restrict__ csr_src,
    const float* __restrict__ s_src, const float* __restrict__ s_dst,
    const __half* __restrict__ h, const float* __restrict__ b,
    const unsigned* __restrict__ gmax_enc, float* __restrict__ out, int n)
{
    __shared__ float bl[64];
    int tid = threadIdx.x;
    if (tid < 64) bl[tid] = b[tid];
    __syncthreads();

    int row = blockIdx.x * 4 + (tid >> 6);
    int lane = tid & 63;
    if (row >= n) return;

    float v = aggregate_row(row, lane, row_off, csr_src, s_src, s_dst, h, bl,
                            dec_f(*gmax_enc));
    out[(size_t)row * 64 + lane] = v;
}

// ---------------------------------------------------------------------------
extern "C" void kernel_launch(void* const* d_in, const int* in_sizes, int n_in,
                              void* d_out, int out_size, void* d_ws, size_t ws_size,
                              hipStream_t stream) {
    const float* x   = (const float*)d_in[0];
    const int*   ei  = (const int*)d_in[1];
    const float* W1  = (const float*)d_in[2];
    const float* a1s = (const float*)d_in[3];
    const float* a1d = (const float*)d_in[4];
    const float* b1  = (const float*)d_in[5];
    const float* W2  = (const float*)d_in[6];
    const float* a2s = (const float*)d_in[7];
    const float* a2d = (const float*)d_in[8];
    const float* b2  = (const float*)d_in[9];
    float* out = (float*)d_out;

    const int* src = ei;
    const int* dst = ei + N_EDGES;

    char* p = (char*)d_ws;
    __half* h   = (__half*)p;           p += (size_t)N_NODES * 64 * 2;
    __half* h2  = (__half*)p;           p += (size_t)N_NODES * 64 * 2;
    float* ssrc = (float*)p;            p += (size_t)N_NODES * 4;
    float* sdst = (float*)p;            p += (size_t)N_NODES * 4;
    float* ssrc2 = (float*)p;           p += (size_t)N_NODES * 4;
    float* sdst2 = (float*)p;           p += (size_t)N_NODES * 4;
    int* row_off = (int*)p;             p += (size_t)(N_NODES + 1) * 4;
    unsigned* gmaxu = (unsigned*)p;     p += 4 * 4;   // [gmax1, gmax2]
    float* bmax = (float*)p;            p += 1024 * 4;
    int* csr_src = (int*)p;             p += (size_t)N_EDGES * 4;
    int* cnt     = (int*)p;             p += (size_t)EBLK * NBKT * 4;
    int* btot    = (int*)p;             p += (size_t)NBKT * 4;
    unsigned* bkted = (unsigned*)p;     p += (size_t)N_EDGES * 4;

    dim3 blk(256);
    int node_blocks = (N_NODES + 3) / 4;

    // K1: gemm1 (x@W1 -> h fp16, scores, bmax) || CSR P1 histogram
    fused_gemm_p1<128><<<GEMM_BLOCKS + EBLK, blk, 0, stream>>>(
        x, W1, a1s, a1d, h, ssrc, sdst, bmax, dst, cnt, N_NODES);
    // K2: CSR P2+P3 fused (redundant scans, no barrier) + gmax1 reduce
    p23_fused<<<EBLK, blk, 0, stream>>>(cnt, btot, bmax, gmaxu, src, dst, bkted);
    // K3: CSR P4
    p4_csr<<<NBKT, blk, 0, stream>>>(bkted, btot, row_off, csr_src);
    // K4: layer-1 aggregation FUSED with gemm2 (h2, s2 scores, gmax2)
    node1_gemm2_kernel<<<node_blocks, blk, 0, stream>>>(
        row_off, csr_src, ssrc, sdst, h, b1, W2, a2s, a2d,
        gmaxu + 0, gmaxu + 1, h2, ssrc2, sdst2, N_NODES);
    // K5: layer-2 aggregation -> d_out
    gat_node_kernel<<<node_blocks, blk, 0, stream>>>(
        row_off, csr_src, ssrc2, sdst2, h2, b2, gmaxu + 1, out, N_NODES);
}

// Round 16
// 136.672 us; speedup vs baseline: 1.6812x; 1.6812x over previous
//
#include <hip/hip_runtime.h>
#include <hip/hip_fp16.h>

#define N_NODES 50000
#define N_EDGES 800000
#define NEG_SLOPE 0.2f
#define NBKT 196            // ceil(50000/256) buckets of 256 nodes
#define EBLK 200            // edge blocks
#define CHUNK 4000          // edges per block (EBLK*CHUNK == N_EDGES)
#define GEMM_BLOCKS 782     // ceil(50000/64)

__device__ __forceinline__ float leaky(float x) { return x >= 0.f ? x : NEG_SLOPE * x; }
__device__ __forceinline__ float readlane_f(float v, int i) {
    return __uint_as_float(__builtin_amdgcn_readlane(__float_as_uint(v), i));
}
// order-preserving float<->uint mapping for atomicMax on mixed-sign floats
__device__ __forceinline__ unsigned enc_f(float f) {
    unsigned u = __float_as_uint(f);
    return (int)u < 0 ? ~u : (u | 0x80000000u);
}
__device__ __forceinline__ float dec_f(unsigned e) {
    return __uint_as_float((int)e < 0 ? (e & 0x7FFFFFFFu) : ~e);
}

// ---------------------------------------------------------------------------
// GEMM body: h(fp16) = x@W, s_src/s_dst (f32). 64x64 tile, BK=32, 4x4/thread.
// Block s_src max -> bmax[blockIdx] (reduced in p23).
// ---------------------------------------------------------------------------
template <int K>
__device__ __forceinline__ void gemm_body(
    const float* __restrict__ x, const float* __restrict__ W,
    const float* __restrict__ a_src, const float* __restrict__ a_dst,
    __half* __restrict__ h, float* __restrict__ s_src, float* __restrict__ s_dst,
    float* __restrict__ bmax, int n)
{
    constexpr int BK = 32;
    __shared__ float Wl[BK][64];
    __shared__ float xt[BK][68];
    __shared__ float asl[64], adl[64];
    __shared__ float wm[4];

    int tid = threadIdx.x;
    if (tid < 64) { asl[tid] = a_src[tid]; adl[tid] = a_dst[tid]; }
    int tx = tid & 15, ty = tid >> 4;
    int row0 = blockIdx.x * 64;

    float acc[4][4] = {};

    for (int k0 = 0; k0 < K; k0 += BK) {
        __syncthreads();
        {
            const float4* Wg = (const float4*)&W[(size_t)k0 * 64];
            float4* Ws = (float4*)&Wl[0][0];
            Ws[tid]       = Wg[tid];
            Ws[tid + 256] = Wg[tid + 256];
        }
        #pragma unroll
        for (int it = 0; it < 2; ++it) {
            int idx = tid + it * 256;
            int r = idx >> 3, kq = idx & 7;
            int grow = row0 + r;
            float4 v = (grow < n) ? *(const float4*)&x[(size_t)grow * K + k0 + kq * 4]
                                  : make_float4(0.f, 0.f, 0.f, 0.f);
            xt[kq * 4 + 0][r] = v.x;
            xt[kq * 4 + 1][r] = v.y;
            xt[kq * 4 + 2][r] = v.z;
            xt[kq * 4 + 3][r] = v.w;
        }
        __syncthreads();

        #pragma unroll
        for (int kk = 0; kk < BK; ++kk) {
            float4 wv = *(const float4*)&Wl[kk][tx * 4];
            float4 xv = *(const float4*)&xt[kk][ty * 4];
            acc[0][0] += xv.x * wv.x; acc[0][1] += xv.x * wv.y; acc[0][2] += xv.x * wv.z; acc[0][3] += xv.x * wv.w;
            acc[1][0] += xv.y * wv.x; acc[1][1] += xv.y * wv.y; acc[1][2] += xv.y * wv.z; acc[1][3] += xv.y * wv.w;
            acc[2][0] += xv.z * wv.x; acc[2][1] += xv.z * wv.y; acc[2][2] += xv.z * wv.z; acc[2][3] += xv.z * wv.w;
            acc[3][0] += xv.w * wv.x; acc[3][1] += xv.w * wv.y; acc[3][2] += xv.w * wv.z; acc[3][3] += xv.w * wv.w;
        }
    }

    float wmax = -INFINITY;
    #pragma unroll
    for (int i = 0; i < 4; ++i) {
        int grow = row0 + ty * 4 + i;
        if (grow < n) {
            __half2 p0 = __floats2half2_rn(acc[i][0], acc[i][1]);
            __half2 p1 = __floats2half2_rn(acc[i][2], acc[i][3]);
            uint2 pk = make_uint2(*(unsigned*)&p0, *(unsigned*)&p1);
            *(uint2*)&h[(size_t)grow * 64 + tx * 4] = pk;
        }
        float s1 = acc[i][0] * asl[tx*4+0] + acc[i][1] * asl[tx*4+1]
                 + acc[i][2] * asl[tx*4+2] + acc[i][3] * asl[tx*4+3];
        float s2 = acc[i][0] * adl[tx*4+0] + acc[i][1] * adl[tx*4+1]
                 + acc[i][2] * adl[tx*4+2] + acc[i][3] * adl[tx*4+3];
        #pragma unroll
        for (int m = 1; m < 16; m <<= 1) {
            s1 += __shfl_xor(s1, m, 64);
            s2 += __shfl_xor(s2, m, 64);
        }
        if (grow < n) wmax = fmaxf(wmax, s1);
        if (tx == 0 && grow < n) { s_src[grow] = s1; s_dst[grow] = s2; }
    }
    wmax = fmaxf(wmax, __shfl_xor(wmax, 16, 64));
    wmax = fmaxf(wmax, __shfl_xor(wmax, 32, 64));
    if ((tid & 63) == 0) wm[tid >> 6] = wmax;
    __syncthreads();
    if (tid == 0)
        bmax[blockIdx.x] = fmaxf(fmaxf(wm[0], wm[1]), fmaxf(wm[2], wm[3]));
}

// K1: gemm1 (blocks 0..781) || CSR P1 histogram (blocks 782..981).
template <int K>
__global__ __launch_bounds__(256) void fused_gemm_p1(
    const float* __restrict__ x, const float* __restrict__ W,
    const float* __restrict__ a_src, const float* __restrict__ a_dst,
    __half* __restrict__ h, float* __restrict__ s_src, float* __restrict__ s_dst,
    float* __restrict__ bmax,
    const int* __restrict__ dst_, int* __restrict__ cnt, int n)
{
    if (blockIdx.x >= GEMM_BLOCKS) {
        __shared__ int bins[NBKT];
        int tid = threadIdx.x, b = blockIdx.x - GEMM_BLOCKS;
        if (tid < NBKT) bins[tid] = 0;
        __syncthreads();
        int e0 = b * CHUNK;
        for (int e = e0 + tid; e < e0 + CHUNK; e += 256)
            atomicAdd(&bins[dst_[e] >> 8], 1);
        __syncthreads();
        if (tid < NBKT) cnt[b * NBKT + tid] = bins[tid];
        return;
    }
    gemm_body<K>(x, W, a_src, a_dst, h, s_src, s_dst, bmax, n);
}

// ---------------------------------------------------------------------------
// K2: P2+P3 fused, barrier-free. Block 0 also writes btot, reduces
// bmax -> gmaxu[0], and zeroes the 64 striped gmax2 slots.
// ---------------------------------------------------------------------------
__global__ __launch_bounds__(256) void p23_fused(
    const int* __restrict__ cnt, int* __restrict__ btot,
    const float* __restrict__ bmax, unsigned* __restrict__ gmaxu,
    unsigned* __restrict__ gslots,
    const int* __restrict__ src, const int* __restrict__ dst,
    unsigned* __restrict__ bkted)
{
    __shared__ int tmp[256];
    __shared__ int boffL[NBKT];
    __shared__ float fm[4];
    int b = blockIdx.x, tid = threadIdx.x;

    int total = 0, myoff = 0;
    if (tid < NBKT) {
        for (int bp = 0; bp < EBLK; ++bp) {
            int v = cnt[bp * NBKT + tid];
            total += v;
            if (bp < b) myoff += v;
        }
    }
    tmp[tid] = (tid < NBKT) ? total : 0;
    __syncthreads();
    for (int off = 1; off < 256; off <<= 1) {
        int a = (tid >= off) ? tmp[tid - off] : 0;
        __syncthreads();
        tmp[tid] += a;
        __syncthreads();
    }
    if (tid < NBKT) {
        int base = tmp[tid] - total;
        boffL[tid] = base + myoff;
        if (b == 0) btot[tid] = total;
    }
    __syncthreads();

    int e0 = b * CHUNK;
    for (int e = e0 + tid; e < e0 + CHUNK; e += 256) {
        int d = dst[e], s = src[e];
        int pos = atomicAdd(&boffL[d >> 8], 1);
        bkted[pos] = ((unsigned)(d & 255) << 16) | (unsigned)s;
    }

    if (b == 0) {
        if (tid < 64) gslots[tid] = 0;          // striped gmax2 slots
        float m = -INFINITY;
        for (int i = tid; i < GEMM_BLOCKS; i += 256) m = fmaxf(m, bmax[i]);
        #pragma unroll
        for (int off = 32; off; off >>= 1) m = fmaxf(m, __shfl_xor(m, off, 64));
        if ((tid & 63) == 0) fm[tid >> 6] = m;
        __syncthreads();
        if (tid == 0)
            gmaxu[0] = enc_f(fmaxf(fmaxf(fm[0], fm[1]), fmaxf(fm[2], fm[3])));
    }
}

// P4: one block per bucket; per-node count/scan/scatter in LDS.
__global__ __launch_bounds__(256) void p4_csr(
    const unsigned* __restrict__ bkted, const int* __restrict__ btot,
    int* __restrict__ row_off, int* __restrict__ csr_src)
{
    __shared__ int tmp[256];
    __shared__ int cur[256];
    __shared__ int s_beg, s_end;
    int j = blockIdx.x, tid = threadIdx.x;
    int v = (tid < NBKT) ? btot[tid] : 0;
    tmp[tid] = v; __syncthreads();
    for (int off = 1; off < 256; off <<= 1) {
        int a = (tid >= off) ? tmp[tid - off] : 0;
        __syncthreads();
        tmp[tid] += a;
        __syncthreads();
    }
    if (tid == j) { s_beg = tmp[tid] - v; s_end = tmp[tid]; }
    cur[tid] = 0;
    __syncthreads();
    int beg = s_beg, end = s_end;

    for (int e = beg + tid; e < end; e += 256)
        atomicAdd(&cur[bkted[e] >> 16], 1);
    __syncthreads();
    int c = cur[tid];
    tmp[tid] = c; __syncthreads();
    for (int off = 1; off < 256; off <<= 1) {
        int a = (tid >= off) ? tmp[tid - off] : 0;
        __syncthreads();
        tmp[tid] += a;
        __syncthreads();
    }
    int offx = tmp[tid] - c;
    int node = j * 256 + tid;
    if (node < N_NODES) row_off[node] = beg + offx;
    if (node == 0) row_off[N_NODES] = N_EDGES;
    __syncthreads();
    cur[tid] = offx;
    __syncthreads();
    for (int e = beg + tid; e < end; e += 256) {
        unsigned u = bkted[e];
        int pos = beg + atomicAdd(&cur[u >> 16], 1);
        csr_src[pos] = (int)(u & 0xFFFFu);
    }
}

// ---------------------------------------------------------------------------
// Shared aggregation (R14-identical paths): per-lane v = weighted-sum/den + b.
// ---------------------------------------------------------------------------
__device__ __forceinline__ float aggregate_row(
    int row, int lane,
    const int* __restrict__ row_off, const int* __restrict__ csr_src,
    const float* __restrict__ s_src, const float* __restrict__ s_dst,
    const __half* __restrict__ h, const float* __restrict__ bvec,
    float m_base)
{
    int beg = row_off[row], end = row_off[row + 1];
    int deg = end - beg;
    float sd = s_dst[row];
    float m = leaky(m_base + sd);               // uniform upper bound, cancels
    float hself = __half2float(h[(size_t)row * 64 + lane]);
    float wself = __expf(leaky(s_src[row] + sd) - m);

    int   mysrc   = row;                        // filler: hot self row, w=0
    float mylogit = -INFINITY;
    if (lane < deg) {
        mysrc = csr_src[beg + lane];
        mylogit = leaky(s_src[mysrc] + sd);
    }
    float w64 = __expf(mylogit - m);
    float den = w64;
    #pragma unroll
    for (int off = 32; off; off >>= 1)
        den += __shfl_xor(den, off, 64);
    den += wself;

    float acc = wself * hself;

    if (deg <= 32) {
        float hv[32];
        #pragma unroll
        for (int j = 0; j < 32; ++j) {
            int s = __builtin_amdgcn_readlane(mysrc, j);
            hv[j] = __half2float(h[(size_t)s * 64 + lane]);
        }
        #pragma unroll
        for (int j = 0; j < 32; ++j)
            acc += readlane_f(w64, j) * hv[j];
    } else {
        int d0 = deg < 64 ? deg : 64;
        int nb = (d0 + 15) & ~15;
        for (int i = 0; i < nb; i += 16) {
            float hv[16];
            #pragma unroll
            for (int j = 0; j < 16; ++j) {
                int s = __builtin_amdgcn_readlane(mysrc, i + j);
                hv[j] = __half2float(h[(size_t)s * 64 + lane]);
            }
            #pragma unroll
            for (int j = 0; j < 16; ++j)
                acc += readlane_f(w64, i + j) * hv[j];
        }
        for (int e = beg + 64; e < end; ++e) {  // deg > 64 tail
            int s = csr_src[e];
            float w = __expf(leaky(s_src[s] + sd) - m);
            den += w;
            acc += w * __half2float(h[(size_t)s * 64 + lane]);
        }
    }
    return acc / den + bvec[lane];
}

// ---------------------------------------------------------------------------
// K4: layer-1 aggregation FUSED with gemm2. gmax2 via 64 STRIPED slots with
// a guarded atomicMax (load first, RMW only if improving) — avoids the
// single-address atomic serialization that cost 150 us in R15.
// ---------------------------------------------------------------------------
__global__ __launch_bounds__(256) void node1_gemm2_kernel(
    const int* __restrict__ row_off, const int* __restrict__ csr_src,
    const float* __restrict__ s_src, const float* __restrict__ s_dst,
    const __half* __restrict__ h, const float* __restrict__ b1,
    const float* __restrict__ W2,
    const float* __restrict__ a2s, const float* __restrict__ a2d,
    const unsigned* __restrict__ gmax1_enc, unsigned* __restrict__ gslots,
    __half* __restrict__ h2, float* __restrict__ s_src2, float* __restrict__ s_dst2,
    int n)
{
    __shared__ float W2l[64][64];
    __shared__ float b1l[64], a2sl[64], a2dl[64];
    __shared__ float wm[4];

    int tid = threadIdx.x;
    {
        const float4* Wg = (const float4*)W2;
        float4* Ws = (float4*)&W2l[0][0];
        #pragma unroll
        for (int it = 0; it < 4; ++it)
            Ws[tid + it * 256] = Wg[tid + it * 256];
        if (tid < 64) { b1l[tid] = b1[tid]; a2sl[tid] = a2s[tid]; a2dl[tid] = a2d[tid]; }
    }
    __syncthreads();

    int row = blockIdx.x * 4 + (tid >> 6);
    int lane = tid & 63;
    float m_base = dec_f(*gmax1_enc);

    float v = 0.f;
    if (row < n) {
        v = aggregate_row(row, lane, row_off, csr_src, s_src, s_dst, h, b1l, m_base);
        v = fmaxf(v, 0.f);                      // ReLU
    }

    // gemm2: acc2[lane] = sum_k v_k * W2[k][lane]
    float acc2 = 0.f;
    #pragma unroll 8
    for (int k = 0; k < 64; ++k) {
        float vk = readlane_f(v, k);
        acc2 += vk * W2l[k][lane];
    }

    float s1 = acc2 * a2sl[lane];
    float s2 = acc2 * a2dl[lane];
    #pragma unroll
    for (int off = 1; off < 64; off <<= 1) {
        s1 += __shfl_xor(s1, off, 64);
        s2 += __shfl_xor(s2, off, 64);
    }

    if (row < n) {
        h2[(size_t)row * 64 + lane] = __float2half(acc2);
        if (lane == 0) { s_src2[row] = s1; s_dst2[row] = s2; }
    }

    float wmax = (row < n) ? s1 : -INFINITY;
    if ((tid & 63) == 0) wm[tid >> 6] = wmax;
    __syncthreads();
    if (tid == 0) {
        float bm = fmaxf(fmaxf(wm[0], wm[1]), fmaxf(wm[2], wm[3]));
        unsigned enc = enc_f(bm);
        unsigned* slot = &gslots[blockIdx.x & 63];
        unsigned cur = __hip_atomic_load(slot, __ATOMIC_RELAXED, __HIP_MEMORY_SCOPE_AGENT);
        if (enc > cur) atomicMax(slot, enc);    // ~5 actual RMWs per slot
    }
}

// ---------------------------------------------------------------------------
// K5: layer-2 aggregation -> d_out. Recovers gmax2 from the 64 striped slots
// (one 64-lane load + wave reduce; L2-hot).
// ---------------------------------------------------------------------------
__global__ __launch_bounds__(256) void gat_node_kernel(
    const int* __restrict__ row_off, const int* __restrict__ csr_src,
    const float* __restrict__ s_src, const float* __restrict__ s_dst,
    const __half* __restrict__ h, const float* __restrict__ b,
    const unsigned* __restrict__ gslots, float* __restrict__ out, int n)
{
    __shared__ float bl[64];
    int tid = threadIdx.x;
    if (tid < 64) bl[tid] = b[tid];
    __syncthreads();

    int row = blockIdx.x * 4 + (tid >> 6);
    int lane = tid & 63;
    if (row >= n) return;

    float m_base = dec_f(gslots[lane]);
    #pragma unroll
    for (int off = 32; off; off >>= 1)
        m_base = fmaxf(m_base, __shfl_xor(m_base, off, 64));

    float v = aggregate_row(row, lane, row_off, csr_src, s_src, s_dst, h, bl, m_base);
    out[(size_t)row * 64 + lane] = v;
}

// ---------------------------------------------------------------------------
extern "C" void kernel_launch(void* const* d_in, const int* in_sizes, int n_in,
                              void* d_out, int out_size, void* d_ws, size_t ws_size,
                              hipStream_t stream) {
    const float* x   = (const float*)d_in[0];
    const int*   ei  = (const int*)d_in[1];
    const float* W1  = (const float*)d_in[2];
    const float* a1s = (const float*)d_in[3];
    const float* a1d = (const float*)d_in[4];
    const float* b1  = (const float*)d_in[5];
    const float* W2  = (const float*)d_in[6];
    const float* a2s = (const float*)d_in[7];
    const float* a2d = (const float*)d_in[8];
    const float* b2  = (const float*)d_in[9];
    float* out = (float*)d_out;

    const int* src = ei;
    const int* dst = ei + N_EDGES;

    char* p = (char*)d_ws;
    __half* h   = (__half*)p;           p += (size_t)N_NODES * 64 * 2;
    __half* h2  = (__half*)p;           p += (size_t)N_NODES * 64 * 2;
    float* ssrc = (float*)p;            p += (size_t)N_NODES * 4;
    float* sdst = (float*)p;            p += (size_t)N_NODES * 4;
    float* ssrc2 = (float*)p;           p += (size_t)N_NODES * 4;
    float* sdst2 = (float*)p;           p += (size_t)N_NODES * 4;
    int* row_off = (int*)p;             p += (size_t)(N_NODES + 1) * 4;
    unsigned* gmaxu = (unsigned*)p;     p += 4 * 4;     // gmax1
    unsigned* gslots = (unsigned*)p;    p += 64 * 4;    // striped gmax2
    float* bmax = (float*)p;            p += 1024 * 4;
    int* csr_src = (int*)p;             p += (size_t)N_EDGES * 4;
    int* cnt     = (int*)p;             p += (size_t)EBLK * NBKT * 4;
    int* btot    = (int*)p;             p += (size_t)NBKT * 4;
    unsigned* bkted = (unsigned*)p;     p += (size_t)N_EDGES * 4;

    dim3 blk(256);
    int node_blocks = (N_NODES + 3) / 4;

    // K1: gemm1 (x@W1 -> h fp16, scores, bmax) || CSR P1 histogram
    fused_gemm_p1<128><<<GEMM_BLOCKS + EBLK, blk, 0, stream>>>(
        x, W1, a1s, a1d, h, ssrc, sdst, bmax, dst, cnt, N_NODES);
    // K2: CSR P2+P3 fused + gmax1 reduce + gslots zero
    p23_fused<<<EBLK, blk, 0, stream>>>(cnt, btot, bmax, gmaxu, gslots, src, dst, bkted);
    // K3: CSR P4
    p4_csr<<<NBKT, blk, 0, stream>>>(bkted, btot, row_off, csr_src);
    // K4: layer-1 aggregation FUSED with gemm2 (h2, s2 scores, striped gmax2)
    node1_gemm2_kernel<<<node_blocks, blk, 0, stream>>>(
        row_off, csr_src, ssrc, sdst, h, b1, W2, a2s, a2d,
        gmaxu + 0, gslots, h2, ssrc2, sdst2, N_NODES);
    // K5: layer-2 aggregation -> d_out
    gat_node_kernel<<<node_blocks, blk, 0, stream>>>(
        row_off, csr_src, ssrc2, sdst2, h2, b2, gslots, out, N_NODES);
}

// Round 17
// 122.423 us; speedup vs baseline: 1.8768x; 1.1164x over previous
//
#include <hip/hip_runtime.h>
#include <hip/hip_fp16.h>

#define N_NODES 50000
#define N_EDGES 800000
#define NEG_SLOPE 0.2f
#define NBKT 196            // ceil(50000/256) buckets of 256 nodes
#define EBLK 200            // edge blocks
#define CHUNK 4000          // edges per block (EBLK*CHUNK == N_EDGES)
#define GEMM_BLOCKS 782     // ceil(50000/64)

__device__ __forceinline__ float leaky(float x) { return x >= 0.f ? x : NEG_SLOPE * x; }
__device__ __forceinline__ float readlane_f(float v, int i) {
    return __uint_as_float(__builtin_amdgcn_readlane(__float_as_uint(v), i));
}
// order-preserving float<->uint mapping for atomicMax on mixed-sign floats
__device__ __forceinline__ unsigned enc_f(float f) {
    unsigned u = __float_as_uint(f);
    return (int)u < 0 ? ~u : (u | 0x80000000u);
}
__device__ __forceinline__ float dec_f(unsigned e) {
    return __uint_as_float((int)e < 0 ? (e & 0x7FFFFFFFu) : ~e);
}

// NL-deep pipelined gather salvo (NL >= wave's deg; fillers carry w=0 and
// hit the L1-hot self row)
template <int NL>
__device__ __forceinline__ float salvo(int mysrc, float w64,
                                       const __half* __restrict__ h,
                                       int lane, float acc)
{
    float hv[NL];
    #pragma unroll
    for (int j = 0; j < NL; ++j) {
        int s = __builtin_amdgcn_readlane(mysrc, j);
        hv[j] = __half2float(h[(size_t)s * 64 + lane]);
    }
    #pragma unroll
    for (int j = 0; j < NL; ++j)
        acc += readlane_f(w64, j) * hv[j];
    return acc;
}

// ---------------------------------------------------------------------------
// GEMM body (R14-identical): h(fp16) = x@W, s_src/s_dst (f32). 64x64 tile,
// BK=32, 4x4/thread. Block s_src max -> bmax (layer1) or atomicMax (layer2).
// ---------------------------------------------------------------------------
template <int K>
__device__ __forceinline__ void gemm_body(
    const float* __restrict__ x, const float* __restrict__ W,
    const float* __restrict__ a_src, const float* __restrict__ a_dst,
    __half* __restrict__ h, float* __restrict__ s_src, float* __restrict__ s_dst,
    float* __restrict__ bmax, unsigned* __restrict__ gmax_enc, int n)
{
    constexpr int BK = 32;
    __shared__ float Wl[BK][64];
    __shared__ float xt[BK][68];
    __shared__ float asl[64], adl[64];
    __shared__ float wm[4];

    int tid = threadIdx.x;
    if (tid < 64) { asl[tid] = a_src[tid]; adl[tid] = a_dst[tid]; }
    int tx = tid & 15, ty = tid >> 4;
    int row0 = blockIdx.x * 64;

    float acc[4][4] = {};

    for (int k0 = 0; k0 < K; k0 += BK) {
        __syncthreads();
        {
            const float4* Wg = (const float4*)&W[(size_t)k0 * 64];
            float4* Ws = (float4*)&Wl[0][0];
            Ws[tid]       = Wg[tid];
            Ws[tid + 256] = Wg[tid + 256];
        }
        #pragma unroll
        for (int it = 0; it < 2; ++it) {
            int idx = tid + it * 256;
            int r = idx >> 3, kq = idx & 7;
            int grow = row0 + r;
            float4 v = (grow < n) ? *(const float4*)&x[(size_t)grow * K + k0 + kq * 4]
                                  : make_float4(0.f, 0.f, 0.f, 0.f);
            xt[kq * 4 + 0][r] = v.x;
            xt[kq * 4 + 1][r] = v.y;
            xt[kq * 4 + 2][r] = v.z;
            xt[kq * 4 + 3][r] = v.w;
        }
        __syncthreads();

        #pragma unroll
        for (int kk = 0; kk < BK; ++kk) {
            float4 wv = *(const float4*)&Wl[kk][tx * 4];
            float4 xv = *(const float4*)&xt[kk][ty * 4];
            acc[0][0] += xv.x * wv.x; acc[0][1] += xv.x * wv.y; acc[0][2] += xv.x * wv.z; acc[0][3] += xv.x * wv.w;
            acc[1][0] += xv.y * wv.x; acc[1][1] += xv.y * wv.y; acc[1][2] += xv.y * wv.z; acc[1][3] += xv.y * wv.w;
            acc[2][0] += xv.z * wv.x; acc[2][1] += xv.z * wv.y; acc[2][2] += xv.z * wv.z; acc[2][3] += xv.z * wv.w;
            acc[3][0] += xv.w * wv.x; acc[3][1] += xv.w * wv.y; acc[3][2] += xv.w * wv.z; acc[3][3] += xv.w * wv.w;
        }
    }

    float wmax = -INFINITY;
    #pragma unroll
    for (int i = 0; i < 4; ++i) {
        int grow = row0 + ty * 4 + i;
        if (grow < n) {
            __half2 p0 = __floats2half2_rn(acc[i][0], acc[i][1]);
            __half2 p1 = __floats2half2_rn(acc[i][2], acc[i][3]);
            uint2 pk = make_uint2(*(unsigned*)&p0, *(unsigned*)&p1);
            *(uint2*)&h[(size_t)grow * 64 + tx * 4] = pk;
        }
        float s1 = acc[i][0] * asl[tx*4+0] + acc[i][1] * asl[tx*4+1]
                 + acc[i][2] * asl[tx*4+2] + acc[i][3] * asl[tx*4+3];
        float s2 = acc[i][0] * adl[tx*4+0] + acc[i][1] * adl[tx*4+1]
                 + acc[i][2] * adl[tx*4+2] + acc[i][3] * adl[tx*4+3];
        #pragma unroll
        for (int m = 1; m < 16; m <<= 1) {
            s1 += __shfl_xor(s1, m, 64);
            s2 += __shfl_xor(s2, m, 64);
        }
        if (grow < n) wmax = fmaxf(wmax, s1);
        if (tx == 0 && grow < n) { s_src[grow] = s1; s_dst[grow] = s2; }
    }
    wmax = fmaxf(wmax, __shfl_xor(wmax, 16, 64));
    wmax = fmaxf(wmax, __shfl_xor(wmax, 32, 64));
    if ((tid & 63) == 0) wm[tid >> 6] = wmax;
    __syncthreads();
    if (tid == 0) {
        float bm = fmaxf(fmaxf(wm[0], wm[1]), fmaxf(wm[2], wm[3]));
        if (bmax) bmax[blockIdx.x] = bm;           // layer 1: reduced in K2
        else      atomicMax(gmax_enc, enc_f(bm));  // layer 2 (782 blocks: cheap)
    }
}

// K1: gemm1 (blocks 0..781) || CSR P1 histogram (blocks 782..981).
template <int K>
__global__ __launch_bounds__(256) void fused_gemm_p1(
    const float* __restrict__ x, const float* __restrict__ W,
    const float* __restrict__ a_src, const float* __restrict__ a_dst,
    __half* __restrict__ h, float* __restrict__ s_src, float* __restrict__ s_dst,
    float* __restrict__ bmax,
    const int* __restrict__ dst_, int* __restrict__ cnt, int n)
{
    if (blockIdx.x >= GEMM_BLOCKS) {
        __shared__ int bins[NBKT];
        int tid = threadIdx.x, b = blockIdx.x - GEMM_BLOCKS;
        if (tid < NBKT) bins[tid] = 0;
        __syncthreads();
        int e0 = b * CHUNK;
        for (int e = e0 + tid; e < e0 + CHUNK; e += 256)
            atomicAdd(&bins[dst_[e] >> 8], 1);
        __syncthreads();
        if (tid < NBKT) cnt[b * NBKT + tid] = bins[tid];
        return;
    }
    gemm_body<K>(x, W, a_src, a_dst, h, s_src, s_dst, bmax, nullptr, n);
}

template <int K>
__global__ __launch_bounds__(256) void gat_gemm_kernel(
    const float* __restrict__ x, const float* __restrict__ W,
    const float* __restrict__ a_src, const float* __restrict__ a_dst,
    __half* __restrict__ h, float* __restrict__ s_src, float* __restrict__ s_dst,
    unsigned* __restrict__ gmax_enc, int n)
{
    gemm_body<K>(x, W, a_src, a_dst, h, s_src, s_dst, nullptr, gmax_enc, n);
}

// ---------------------------------------------------------------------------
// K2: P2+P3 fused, barrier-free (R14-identical). Block 0 also writes btot,
// reduces bmax -> gmaxu[0], zeroes gmaxu[1].
// ---------------------------------------------------------------------------
__global__ __launch_bounds__(256) void p23_fused(
    const int* __restrict__ cnt, int* __restrict__ btot,
    const float* __restrict__ bmax, unsigned* __restrict__ gmaxu,
    const int* __restrict__ src, const int* __restrict__ dst,
    unsigned* __restrict__ bkted)
{
    __shared__ int tmp[256];
    __shared__ int boffL[NBKT];
    __shared__ float fm[4];
    int b = blockIdx.x, tid = threadIdx.x;

    int total = 0, myoff = 0;
    if (tid < NBKT) {
        for (int bp = 0; bp < EBLK; ++bp) {
            int v = cnt[bp * NBKT + tid];
            total += v;
            if (bp < b) myoff += v;
        }
    }
    tmp[tid] = (tid < NBKT) ? total : 0;
    __syncthreads();
    for (int off = 1; off < 256; off <<= 1) {
        int a = (tid >= off) ? tmp[tid - off] : 0;
        __syncthreads();
        tmp[tid] += a;
        __syncthreads();
    }
    if (tid < NBKT) {
        int base = tmp[tid] - total;
        boffL[tid] = base + myoff;
        if (b == 0) btot[tid] = total;
    }
    __syncthreads();

    int e0 = b * CHUNK;
    for (int e = e0 + tid; e < e0 + CHUNK; e += 256) {
        int d = dst[e], s = src[e];
        int pos = atomicAdd(&boffL[d >> 8], 1);
        bkted[pos] = ((unsigned)(d & 255) << 16) | (unsigned)s;
    }

    if (b == 0) {
        float m = -INFINITY;
        for (int i = tid; i < GEMM_BLOCKS; i += 256) m = fmaxf(m, bmax[i]);
        #pragma unroll
        for (int off = 32; off; off >>= 1) m = fmaxf(m, __shfl_xor(m, off, 64));
        if ((tid & 63) == 0) fm[tid >> 6] = m;
        __syncthreads();
        if (tid == 0) {
            gmaxu[0] = enc_f(fmaxf(fmaxf(fm[0], fm[1]), fmaxf(fm[2], fm[3])));
            gmaxu[1] = 0;
        }
    }
}

// P4: one block per bucket; per-node count/scan/scatter in LDS (R14-identical).
__global__ __launch_bounds__(256) void p4_csr(
    const unsigned* __restrict__ bkted, const int* __restrict__ btot,
    int* __restrict__ row_off, int* __restrict__ csr_src)
{
    __shared__ int tmp[256];
    __shared__ int cur[256];
    __shared__ int s_beg, s_end;
    int j = blockIdx.x, tid = threadIdx.x;
    int v = (tid < NBKT) ? btot[tid] : 0;
    tmp[tid] = v; __syncthreads();
    for (int off = 1; off < 256; off <<= 1) {
        int a = (tid >= off) ? tmp[tid - off] : 0;
        __syncthreads();
        tmp[tid] += a;
        __syncthreads();
    }
    if (tid == j) { s_beg = tmp[tid] - v; s_end = tmp[tid]; }
    cur[tid] = 0;
    __syncthreads();
    int beg = s_beg, end = s_end;

    for (int e = beg + tid; e < end; e += 256)
        atomicAdd(&cur[bkted[e] >> 16], 1);
    __syncthreads();
    int c = cur[tid];
    tmp[tid] = c; __syncthreads();
    for (int off = 1; off < 256; off <<= 1) {
        int a = (tid >= off) ? tmp[tid - off] : 0;
        __syncthreads();
        tmp[tid] += a;
        __syncthreads();
    }
    int offx = tmp[tid] - c;
    int node = j * 256 + tid;
    if (node < N_NODES) row_off[node] = beg + offx;
    if (node == 0) row_off[N_NODES] = N_EDGES;
    __syncthreads();
    cur[tid] = offx;
    __syncthreads();
    for (int e = beg + tid; e < end; e += 256) {
        unsigned u = bkted[e];
        int pos = beg + atomicAdd(&cur[u >> 16], 1);
        csr_src[pos] = (int)(u & 0xFFFFu);
    }
}

// ---------------------------------------------------------------------------
// Fused per-node attention kernel (R14 + deg<=16 tier). One wave per node;
// fp16 h gathers (128 B row = one line); global-max bound -> no max pass.
// ---------------------------------------------------------------------------
template <bool RELU>
__global__ __launch_bounds__(256) void gat_node_kernel(
    const int* __restrict__ row_off, const int* __restrict__ csr_src,
    const float* __restrict__ s_src, const float* __restrict__ s_dst,
    const __half* __restrict__ h, const float* __restrict__ b,
    const unsigned* __restrict__ gmax_enc, float* __restrict__ out, int n)
{
    int row = blockIdx.x * 4 + (threadIdx.x >> 6);
    int lane = threadIdx.x & 63;
    if (row >= n) return;

    int beg = row_off[row], end = row_off[row + 1];
    int deg = end - beg;
    float sd = s_dst[row];
    float m = leaky(dec_f(*gmax_enc) + sd);
    float s_self = s_src[row];
    float hself = __half2float(h[(size_t)row * 64 + lane]);
    float wself = __expf(leaky(s_self + sd) - m);

    if (deg <= 32) {
        int mysrc = row;
        if (lane < deg) mysrc = csr_src[beg + lane];
        float my_s = s_src[mysrc];
        float mylogit = (lane < deg) ? leaky(my_s + sd) : -INFINITY;
        float w64 = __expf(mylogit - m);
        float den = w64;
        #pragma unroll
        for (int off = 32; off; off >>= 1)
            den += __shfl_xor(den, off, 64);
        den += wself;

        float acc = wself * hself;
        if (deg <= 16) acc = salvo<16>(mysrc, w64, h, lane, acc);  // ~54% of nodes
        else           acc = salvo<32>(mysrc, w64, h, lane, acc);

        float v = acc / den + b[lane];
        if (RELU) v = fmaxf(v, 0.f);
        out[(size_t)row * 64 + lane] = v;
        return;
    }

    // generic path: deg > 32
    int   mysrc   = row;
    float mylogit = -INFINITY;
    if (lane < deg) {
        mysrc = csr_src[beg + lane];
        mylogit = leaky(s_src[mysrc] + sd);
    }
    float w64 = __expf(mylogit - m);
    float den = w64;
    #pragma unroll
    for (int off = 32; off; off >>= 1)
        den += __shfl_xor(den, off, 64);
    den += wself;

    float acc = wself * hself;
    int d0 = deg < 64 ? deg : 64;
    int nb = (d0 + 15) & ~15;
    for (int i = 0; i < nb; i += 16) {
        float hv[16];
        #pragma unroll
        for (int j = 0; j < 16; ++j) {
            int s = __builtin_amdgcn_readlane(mysrc, i + j);
            hv[j] = __half2float(h[(size_t)s * 64 + lane]);
        }
        #pragma unroll
        for (int j = 0; j < 16; ++j)
            acc += readlane_f(w64, i + j) * hv[j];
    }
    for (int e = beg + 64; e < end; ++e) {
        int s = csr_src[e];
        float w = __expf(leaky(s_src[s] + sd) - m);
        den += w;
        acc += w * __half2float(h[(size_t)s * 64 + lane]);
    }

    float v = acc / den + b[lane];
    if (RELU) v = fmaxf(v, 0.f);
    out[(size_t)row * 64 + lane] = v;
}

// ---------------------------------------------------------------------------
extern "C" void kernel_launch(void* const* d_in, const int* in_sizes, int n_in,
                              void* d_out, int out_size, void* d_ws, size_t ws_size,
                              hipStream_t stream) {
    const float* x   = (const float*)d_in[0];
    const int*   ei  = (const int*)d_in[1];
    const float* W1  = (const float*)d_in[2];
    const float* a1s = (const float*)d_in[3];
    const float* a1d = (const float*)d_in[4];
    const float* b1  = (const float*)d_in[5];
    const float* W2  = (const float*)d_in[6];
    const float* a2s = (const float*)d_in[7];
    const float* a2d = (const float*)d_in[8];
    const float* b2  = (const float*)d_in[9];
    float* out = (float*)d_out;

    const int* src = ei;
    const int* dst = ei + N_EDGES;

    char* p = (char*)d_ws;
    __half* h   = (__half*)p;           p += (size_t)N_NODES * 64 * 2;
    float* ssrc = (float*)p;            p += (size_t)N_NODES * 4;
    float* sdst = (float*)p;            p += (size_t)N_NODES * 4;
    int* row_off = (int*)p;             p += (size_t)(N_NODES + 1) * 4;
    unsigned* gmaxu = (unsigned*)p;     p += 4 * 4;   // [gmax1, gmax2]
    float* bmax = (float*)p;            p += 1024 * 4;
    int* csr_src = (int*)p;             p += (size_t)N_EDGES * 4;
    int* cnt     = (int*)p;             p += (size_t)EBLK * NBKT * 4;
    int* btot    = (int*)p;             p += (size_t)NBKT * 4;
    unsigned* bkted = (unsigned*)p;     p += (size_t)N_EDGES * 4;  // own buffer (h live)

    dim3 blk(256);
    int node_blocks = (N_NODES + 3) / 4;

    // K1: gemm1 (x@W1 -> h fp16, scores, bmax) || CSR P1 histogram
    fused_gemm_p1<128><<<GEMM_BLOCKS + EBLK, blk, 0, stream>>>(
        x, W1, a1s, a1d, h, ssrc, sdst, bmax, dst, cnt, N_NODES);
    // K2: CSR P2+P3 fused (redundant scans, no barrier) + gmax1 reduce
    p23_fused<<<EBLK, blk, 0, stream>>>(cnt, btot, bmax, gmaxu, src, dst, bkted);
    // K3: CSR P4
    p4_csr<<<NBKT, blk, 0, stream>>>(bkted, btot, row_off, csr_src);
    // K4: layer-1 aggregation
    gat_node_kernel<true><<<node_blocks, blk, 0, stream>>>(
        row_off, csr_src, ssrc, sdst, h, b1, gmaxu + 0, out, N_NODES);
    // K5: gemm2
    gat_gemm_kernel<64><<<GEMM_BLOCKS, blk, 0, stream>>>(
        out, W2, a2s, a2d, h, ssrc, sdst, gmaxu + 1, N_NODES);
    // K6: layer-2 aggregation
    gat_node_kernel<false><<<node_blocks, blk, 0, stream>>>(
        row_off, csr_src, ssrc, sdst, h, b2, gmaxu + 1, out, N_NODES);
}

// Round 18
// 122.264 us; speedup vs baseline: 1.8793x; 1.0013x over previous
//
#include <hip/hip_runtime.h>
#include <hip/hip_fp16.h>
#include <type_traits>

#define N_NODES 50000
#define N_EDGES 800000
#define NEG_SLOPE 0.2f
#define NBKT 196            // ceil(50000/256) buckets of 256 nodes
#define EBLK 200            // edge blocks
#define CHUNK 4000          // edges per block (EBLK*CHUNK == N_EDGES)
#define GEMM_BLOCKS 782     // ceil(50000/64)

__device__ __forceinline__ float leaky(float x) { return x >= 0.f ? x : NEG_SLOPE * x; }
__device__ __forceinline__ float readlane_f(float v, int i) {
    return __uint_as_float(__builtin_amdgcn_readlane(__float_as_uint(v), i));
}
// order-preserving float<->uint mapping for atomicMax on mixed-sign floats
__device__ __forceinline__ unsigned enc_f(float f) {
    unsigned u = __float_as_uint(f);
    return (int)u < 0 ? ~u : (u | 0x80000000u);
}
__device__ __forceinline__ float dec_f(unsigned e) {
    return __uint_as_float((int)e < 0 ? (e & 0x7FFFFFFFu) : ~e);
}

// NL-deep pipelined gather salvo (NL >= wave's deg; fillers carry w=0 and
// hit the L1-hot self row)
template <int NL>
__device__ __forceinline__ float salvo(int mysrc, float w64,
                                       const __half* __restrict__ h,
                                       int lane, float acc)
{
    float hv[NL];
    #pragma unroll
    for (int j = 0; j < NL; ++j) {
        int s = __builtin_amdgcn_readlane(mysrc, j);
        hv[j] = __half2float(h[(size_t)s * 64 + lane]);
    }
    #pragma unroll
    for (int j = 0; j < NL; ++j)
        acc += readlane_f(w64, j) * hv[j];
    return acc;
}

// ---------------------------------------------------------------------------
// GEMM body: h(fp16) = x@W, s_src/s_dst (f32). 64x64 tile, BK=32, 4x4/thread.
// XT = float (layer 1) or __half (layer 2 input = fp16 layer-1 activations).
// Block s_src max -> bmax (layer1) or atomicMax (layer2).
// ---------------------------------------------------------------------------
template <int K, typename XT>
__device__ __forceinline__ void gemm_body(
    const XT* __restrict__ x, const float* __restrict__ W,
    const float* __restrict__ a_src, const float* __restrict__ a_dst,
    __half* __restrict__ h, float* __restrict__ s_src, float* __restrict__ s_dst,
    float* __restrict__ bmax, unsigned* __restrict__ gmax_enc, int n)
{
    constexpr int BK = 32;
    __shared__ float Wl[BK][64];
    __shared__ float xt[BK][68];
    __shared__ float asl[64], adl[64];
    __shared__ float wm[4];

    int tid = threadIdx.x;
    if (tid < 64) { asl[tid] = a_src[tid]; adl[tid] = a_dst[tid]; }
    int tx = tid & 15, ty = tid >> 4;
    int row0 = blockIdx.x * 64;

    float acc[4][4] = {};

    for (int k0 = 0; k0 < K; k0 += BK) {
        __syncthreads();
        {
            const float4* Wg = (const float4*)&W[(size_t)k0 * 64];
            float4* Ws = (float4*)&Wl[0][0];
            Ws[tid]       = Wg[tid];
            Ws[tid + 256] = Wg[tid + 256];
        }
        #pragma unroll
        for (int it = 0; it < 2; ++it) {
            int idx = tid + it * 256;
            int r = idx >> 3, kq = idx & 7;
            int grow = row0 + r;
            float4 v;
            if constexpr (std::is_same<XT, float>::value) {
                v = (grow < n) ? *(const float4*)&x[(size_t)grow * K + k0 + kq * 4]
                               : make_float4(0.f, 0.f, 0.f, 0.f);
            } else {
                if (grow < n) {
                    uint2 raw = *(const uint2*)&x[(size_t)grow * K + k0 + kq * 4];
                    float2 lo = __half22float2(*(__half2*)&raw.x);
                    float2 hi = __half22float2(*(__half2*)&raw.y);
                    v = make_float4(lo.x, lo.y, hi.x, hi.y);
                } else {
                    v = make_float4(0.f, 0.f, 0.f, 0.f);
                }
            }
            xt[kq * 4 + 0][r] = v.x;
            xt[kq * 4 + 1][r] = v.y;
            xt[kq * 4 + 2][r] = v.z;
            xt[kq * 4 + 3][r] = v.w;
        }
        __syncthreads();

        #pragma unroll
        for (int kk = 0; kk < BK; ++kk) {
            float4 wv = *(const float4*)&Wl[kk][tx * 4];
            float4 xv = *(const float4*)&xt[kk][ty * 4];
            acc[0][0] += xv.x * wv.x; acc[0][1] += xv.x * wv.y; acc[0][2] += xv.x * wv.z; acc[0][3] += xv.x * wv.w;
            acc[1][0] += xv.y * wv.x; acc[1][1] += xv.y * wv.y; acc[1][2] += xv.y * wv.z; acc[1][3] += xv.y * wv.w;
            acc[2][0] += xv.z * wv.x; acc[2][1] += xv.z * wv.y; acc[2][2] += xv.z * wv.z; acc[2][3] += xv.z * wv.w;
            acc[3][0] += xv.w * wv.x; acc[3][1] += xv.w * wv.y; acc[3][2] += xv.w * wv.z; acc[3][3] += xv.w * wv.w;
        }
    }

    float wmax = -INFINITY;
    #pragma unroll
    for (int i = 0; i < 4; ++i) {
        int grow = row0 + ty * 4 + i;
        if (grow < n) {
            __half2 p0 = __floats2half2_rn(acc[i][0], acc[i][1]);
            __half2 p1 = __floats2half2_rn(acc[i][2], acc[i][3]);
            uint2 pk = make_uint2(*(unsigned*)&p0, *(unsigned*)&p1);
            *(uint2*)&h[(size_t)grow * 64 + tx * 4] = pk;
        }
        float s1 = acc[i][0] * asl[tx*4+0] + acc[i][1] * asl[tx*4+1]
                 + acc[i][2] * asl[tx*4+2] + acc[i][3] * asl[tx*4+3];
        float s2 = acc[i][0] * adl[tx*4+0] + acc[i][1] * adl[tx*4+1]
                 + acc[i][2] * adl[tx*4+2] + acc[i][3] * adl[tx*4+3];
        #pragma unroll
        for (int m = 1; m < 16; m <<= 1) {
            s1 += __shfl_xor(s1, m, 64);
            s2 += __shfl_xor(s2, m, 64);
        }
        if (grow < n) wmax = fmaxf(wmax, s1);
        if (tx == 0 && grow < n) { s_src[grow] = s1; s_dst[grow] = s2; }
    }
    wmax = fmaxf(wmax, __shfl_xor(wmax, 16, 64));
    wmax = fmaxf(wmax, __shfl_xor(wmax, 32, 64));
    if ((tid & 63) == 0) wm[tid >> 6] = wmax;
    __syncthreads();
    if (tid == 0) {
        float bm = fmaxf(fmaxf(wm[0], wm[1]), fmaxf(wm[2], wm[3]));
        if (bmax) bmax[blockIdx.x] = bm;           // layer 1: reduced in K2
        else      atomicMax(gmax_enc, enc_f(bm));  // layer 2 (782 blocks: cheap)
    }
}

// K1: gemm1 (blocks 0..781) || CSR P1 histogram (blocks 782..981).
template <int K>
__global__ __launch_bounds__(256) void fused_gemm_p1(
    const float* __restrict__ x, const float* __restrict__ W,
    const float* __restrict__ a_src, const float* __restrict__ a_dst,
    __half* __restrict__ h, float* __restrict__ s_src, float* __restrict__ s_dst,
    float* __restrict__ bmax,
    const int* __restrict__ dst_, int* __restrict__ cnt, int n)
{
    if (blockIdx.x >= GEMM_BLOCKS) {
        __shared__ int bins[NBKT];
        int tid = threadIdx.x, b = blockIdx.x - GEMM_BLOCKS;
        if (tid < NBKT) bins[tid] = 0;
        __syncthreads();
        int e0 = b * CHUNK;
        for (int e = e0 + tid; e < e0 + CHUNK; e += 256)
            atomicAdd(&bins[dst_[e] >> 8], 1);
        __syncthreads();
        if (tid < NBKT) cnt[b * NBKT + tid] = bins[tid];
        return;
    }
    gemm_body<K, float>(x, W, a_src, a_dst, h, s_src, s_dst, bmax, nullptr, n);
}

// K5: gemm2, reading fp16 layer-1 activations.
template <int K>
__global__ __launch_bounds__(256) void gat_gemm_kernel_h(
    const __half* __restrict__ x, const float* __restrict__ W,
    const float* __restrict__ a_src, const float* __restrict__ a_dst,
    __half* __restrict__ h, float* __restrict__ s_src, float* __restrict__ s_dst,
    unsigned* __restrict__ gmax_enc, int n)
{
    gemm_body<K, __half>(x, W, a_src, a_dst, h, s_src, s_dst, nullptr, gmax_enc, n);
}

// ---------------------------------------------------------------------------
// K2: P2+P3 fused, barrier-free. Block 0 also writes btot, reduces
// bmax -> gmaxu[0], zeroes gmaxu[1].
// ---------------------------------------------------------------------------
__global__ __launch_bounds__(256) void p23_fused(
    const int* __restrict__ cnt, int* __restrict__ btot,
    const float* __restrict__ bmax, unsigned* __restrict__ gmaxu,
    const int* __restrict__ src, const int* __restrict__ dst,
    unsigned* __restrict__ bkted)
{
    __shared__ int tmp[256];
    __shared__ int boffL[NBKT];
    __shared__ float fm[4];
    int b = blockIdx.x, tid = threadIdx.x;

    int total = 0, myoff = 0;
    if (tid < NBKT) {
        for (int bp = 0; bp < EBLK; ++bp) {
            int v = cnt[bp * NBKT + tid];
            total += v;
            if (bp < b) myoff += v;
        }
    }
    tmp[tid] = (tid < NBKT) ? total : 0;
    __syncthreads();
    for (int off = 1; off < 256; off <<= 1) {
        int a = (tid >= off) ? tmp[tid - off] : 0;
        __syncthreads();
        tmp[tid] += a;
        __syncthreads();
    }
    if (tid < NBKT) {
        int base = tmp[tid] - total;
        boffL[tid] = base + myoff;
        if (b == 0) btot[tid] = total;
    }
    __syncthreads();

    int e0 = b * CHUNK;
    for (int e = e0 + tid; e < e0 + CHUNK; e += 256) {
        int d = dst[e], s = src[e];
        int pos = atomicAdd(&boffL[d >> 8], 1);
        bkted[pos] = ((unsigned)(d & 255) << 16) | (unsigned)s;
    }

    if (b == 0) {
        float m = -INFINITY;
        for (int i = tid; i < GEMM_BLOCKS; i += 256) m = fmaxf(m, bmax[i]);
        #pragma unroll
        for (int off = 32; off; off >>= 1) m = fmaxf(m, __shfl_xor(m, off, 64));
        if ((tid & 63) == 0) fm[tid >> 6] = m;
        __syncthreads();
        if (tid == 0) {
            gmaxu[0] = enc_f(fmaxf(fmaxf(fm[0], fm[1]), fmaxf(fm[2], fm[3])));
            gmaxu[1] = 0;
        }
    }
}

// P4: one block per bucket; per-node count/scan/scatter in LDS.
__global__ __launch_bounds__(256) void p4_csr(
    const unsigned* __restrict__ bkted, const int* __restrict__ btot,
    int* __restrict__ row_off, int* __restrict__ csr_src)
{
    __shared__ int tmp[256];
    __shared__ int cur[256];
    __shared__ int s_beg, s_end;
    int j = blockIdx.x, tid = threadIdx.x;
    int v = (tid < NBKT) ? btot[tid] : 0;
    tmp[tid] = v; __syncthreads();
    for (int off = 1; off < 256; off <<= 1) {
        int a = (tid >= off) ? tmp[tid - off] : 0;
        __syncthreads();
        tmp[tid] += a;
        __syncthreads();
    }
    if (tid == j) { s_beg = tmp[tid] - v; s_end = tmp[tid]; }
    cur[tid] = 0;
    __syncthreads();
    int beg = s_beg, end = s_end;

    for (int e = beg + tid; e < end; e += 256)
        atomicAdd(&cur[bkted[e] >> 16], 1);
    __syncthreads();
    int c = cur[tid];
    tmp[tid] = c; __syncthreads();
    for (int off = 1; off < 256; off <<= 1) {
        int a = (tid >= off) ? tmp[tid - off] : 0;
        __syncthreads();
        tmp[tid] += a;
        __syncthreads();
    }
    int offx = tmp[tid] - c;
    int node = j * 256 + tid;
    if (node < N_NODES) row_off[node] = beg + offx;
    if (node == 0) row_off[N_NODES] = N_EDGES;
    __syncthreads();
    cur[tid] = offx;
    __syncthreads();
    for (int e = beg + tid; e < end; e += 256) {
        unsigned u = bkted[e];
        int pos = beg + atomicAdd(&cur[u >> 16], 1);
        csr_src[pos] = (int)(u & 0xFFFFu);
    }
}

// ---------------------------------------------------------------------------
// Fused per-node attention kernel (R17 structure). OT = __half (layer 1,
// fp16 scratch out) or float (layer 2, d_out). One wave per node; fp16 h
// gathers (128 B row = one line); global-max bound -> no max pass.
// ---------------------------------------------------------------------------
template <bool RELU, typename OT>
__global__ __launch_bounds__(256) void gat_node_kernel(
    const int* __restrict__ row_off, const int* __restrict__ csr_src,
    const float* __restrict__ s_src, const float* __restrict__ s_dst,
    const __half* __restrict__ h, const float* __restrict__ b,
    const unsigned* __restrict__ gmax_enc, OT* __restrict__ out, int n)
{
    int row = blockIdx.x * 4 + (threadIdx.x >> 6);
    int lane = threadIdx.x & 63;
    if (row >= n) return;

    int beg = row_off[row], end = row_off[row + 1];
    int deg = end - beg;
    float sd = s_dst[row];
    float m = leaky(dec_f(*gmax_enc) + sd);
    float s_self = s_src[row];
    float hself = __half2float(h[(size_t)row * 64 + lane]);
    float wself = __expf(leaky(s_self + sd) - m);

    float v;
    if (deg <= 32) {
        int mysrc = row;
        if (lane < deg) mysrc = csr_src[beg + lane];
        float my_s = s_src[mysrc];
        float mylogit = (lane < deg) ? leaky(my_s + sd) : -INFINITY;
        float w64 = __expf(mylogit - m);
        float den = w64;
        #pragma unroll
        for (int off = 32; off; off >>= 1)
            den += __shfl_xor(den, off, 64);
        den += wself;

        float acc = wself * hself;
        if (deg <= 16) acc = salvo<16>(mysrc, w64, h, lane, acc);  // ~54% of nodes
        else           acc = salvo<32>(mysrc, w64, h, lane, acc);
        v = acc / den + b[lane];
    } else {
        // generic path: deg > 32
        int   mysrc   = row;
        float mylogit = -INFINITY;
        if (lane < deg) {
            mysrc = csr_src[beg + lane];
            mylogit = leaky(s_src[mysrc] + sd);
        }
        float w64 = __expf(mylogit - m);
        float den = w64;
        #pragma unroll
        for (int off = 32; off; off >>= 1)
            den += __shfl_xor(den, off, 64);
        den += wself;

        float acc = wself * hself;
        int d0 = deg < 64 ? deg : 64;
        int nb = (d0 + 15) & ~15;
        for (int i = 0; i < nb; i += 16) {
            float hv[16];
            #pragma unroll
            for (int j = 0; j < 16; ++j) {
                int s = __builtin_amdgcn_readlane(mysrc, i + j);
                hv[j] = __half2float(h[(size_t)s * 64 + lane]);
            }
            #pragma unroll
            for (int j = 0; j < 16; ++j)
                acc += readlane_f(w64, i + j) * hv[j];
        }
        for (int e = beg + 64; e < end; ++e) {
            int s = csr_src[e];
            float w = __expf(leaky(s_src[s] + sd) - m);
            den += w;
            acc += w * __half2float(h[(size_t)s * 64 + lane]);
        }
        v = acc / den + b[lane];
    }

    if (RELU) v = fmaxf(v, 0.f);
    if constexpr (std::is_same<OT, __half>::value)
        out[(size_t)row * 64 + lane] = __float2half(v);
    else
        out[(size_t)row * 64 + lane] = v;
}

// ---------------------------------------------------------------------------
extern "C" void kernel_launch(void* const* d_in, const int* in_sizes, int n_in,
                              void* d_out, int out_size, void* d_ws, size_t ws_size,
                              hipStream_t stream) {
    const float* x   = (const float*)d_in[0];
    const int*   ei  = (const int*)d_in[1];
    const float* W1  = (const float*)d_in[2];
    const float* a1s = (const float*)d_in[3];
    const float* a1d = (const float*)d_in[4];
    const float* b1  = (const float*)d_in[5];
    const float* W2  = (const float*)d_in[6];
    const float* a2s = (const float*)d_in[7];
    const float* a2d = (const float*)d_in[8];
    const float* b2  = (const float*)d_in[9];
    float* out = (float*)d_out;

    const int* src = ei;
    const int* dst = ei + N_EDGES;

    char* p = (char*)d_ws;
    __half* h    = (__half*)p;          p += (size_t)N_NODES * 64 * 2;
    __half* outh = (__half*)p;          p += (size_t)N_NODES * 64 * 2;  // fp16 layer-1 out
    float* ssrc = (float*)p;            p += (size_t)N_NODES * 4;
    float* sdst = (float*)p;            p += (size_t)N_NODES * 4;
    int* row_off = (int*)p;             p += (size_t)(N_NODES + 1) * 4;
    unsigned* gmaxu = (unsigned*)p;     p += 4 * 4;   // [gmax1, gmax2]
    float* bmax = (float*)p;            p += 1024 * 4;
    int* csr_src = (int*)p;             p += (size_t)N_EDGES * 4;
    int* cnt     = (int*)p;             p += (size_t)EBLK * NBKT * 4;
    int* btot    = (int*)p;             p += (size_t)NBKT * 4;
    unsigned* bkted = (unsigned*)p;     p += (size_t)N_EDGES * 4;  // own buffer (h live)

    dim3 blk(256);
    int node_blocks = (N_NODES + 3) / 4;

    // K1: gemm1 (x@W1 -> h fp16, scores, bmax) || CSR P1 histogram
    fused_gemm_p1<128><<<GEMM_BLOCKS + EBLK, blk, 0, stream>>>(
        x, W1, a1s, a1d, h, ssrc, sdst, bmax, dst, cnt, N_NODES);
    // K2: CSR P2+P3 fused (redundant scans, no barrier) + gmax1 reduce
    p23_fused<<<EBLK, blk, 0, stream>>>(cnt, btot, bmax, gmaxu, src, dst, bkted);
    // K3: CSR P4
    p4_csr<<<NBKT, blk, 0, stream>>>(bkted, btot, row_off, csr_src);
    // K4: layer-1 aggregation -> fp16 scratch (never touches d_out)
    gat_node_kernel<true, __half><<<node_blocks, blk, 0, stream>>>(
        row_off, csr_src, ssrc, sdst, h, b1, gmaxu + 0, outh, N_NODES);
    // K5: gemm2 (fp16 input)
    gat_gemm_kernel_h<64><<<GEMM_BLOCKS, blk, 0, stream>>>(
        outh, W2, a2s, a2d, h, ssrc, sdst, gmaxu + 1, N_NODES);
    // K6: layer-2 aggregation -> d_out
    gat_node_kernel<false, float><<<node_blocks, blk, 0, stream>>>(
        row_off, csr_src, ssrc, sdst, h, b2, gmaxu + 1, out, N_NODES);
}

// Round 19
// 116.525 us; speedup vs baseline: 1.9718x; 1.0492x over previous
//
#include <hip/hip_runtime.h>
#include <hip/hip_fp16.h>
#include <type_traits>

#define N_NODES 50000
#define N_EDGES 800000
#define NEG_SLOPE 0.2f
#define NBKT 196            // ceil(50000/256) buckets of 256 nodes
#define EBLK 200            // edge blocks
#define CHUNK 4000          // edges per block (EBLK*CHUNK == N_EDGES)
#define GEMM_BLOCKS 782     // ceil(50000/64)

typedef __attribute__((ext_vector_type(8))) short short8v;   // 8 bf16 (4 VGPRs)
typedef __attribute__((ext_vector_type(4))) float f32x4;     // MFMA accumulator

__device__ __forceinline__ float leaky(float x) { return x >= 0.f ? x : NEG_SLOPE * x; }
__device__ __forceinline__ float readlane_f(float v, int i) {
    return __uint_as_float(__builtin_amdgcn_readlane(__float_as_uint(v), i));
}
// order-preserving float<->uint mapping for atomicMax on mixed-sign floats
__device__ __forceinline__ unsigned enc_f(float f) {
    unsigned u = __float_as_uint(f);
    return (int)u < 0 ? ~u : (u | 0x80000000u);
}
__device__ __forceinline__ float dec_f(unsigned e) {
    return __uint_as_float((int)e < 0 ? (e & 0x7FFFFFFFu) : ~e);
}
// f32 -> bf16 bits, round-to-nearest-even
__device__ __forceinline__ unsigned short f2bf_bits(float f) {
    unsigned u = __float_as_uint(f);
    unsigned r = u + 0x7FFFu + ((u >> 16) & 1u);
    return (unsigned short)(r >> 16);
}

// NL-deep pipelined gather salvo (NL >= wave's deg; fillers carry w=0 and
// hit the L1-hot self row)
template <int NL>
__device__ __forceinline__ float salvo(int mysrc, float w64,
                                       const __half* __restrict__ h,
                                       int lane, float acc)
{
    float hv[NL];
    #pragma unroll
    for (int j = 0; j < NL; ++j) {
        int s = __builtin_amdgcn_readlane(mysrc, j);
        hv[j] = __half2float(h[(size_t)s * 64 + lane]);
    }
    #pragma unroll
    for (int j = 0; j < NL; ++j)
        acc += readlane_f(w64, j) * hv[j];
    return acc;
}

// ---------------------------------------------------------------------------
// K1: MFMA gemm1 (blocks 0..781) || CSR P1 histogram (blocks 782..981).
// gemm part: h(fp16) = bf16(x) @ bf16(W1) with f32 accumulate via
// v_mfma_f32_16x16x32_bf16. Block tile 64 rows x 64 cols, K=128 in 4 steps.
// Wave w owns rows 16w..16w+15; 4 col-tiles of 16. C/D layout (HW-verified):
// col = lane&15, row = (lane>>4)*4 + reg. Epilogue: h fp16 write + s-scores
// (16-lane shfl reduce) + block max -> bmax.
// ---------------------------------------------------------------------------
__global__ __launch_bounds__(256) void fused_gemm1_p1(
    const float* __restrict__ x, const float* __restrict__ W,
    const float* __restrict__ a_src, const float* __restrict__ a_dst,
    __half* __restrict__ h, float* __restrict__ s_src, float* __restrict__ s_dst,
    float* __restrict__ bmax,
    const int* __restrict__ dst_, int* __restrict__ cnt, int n)
{
    if (blockIdx.x >= GEMM_BLOCKS) {
        __shared__ int bins[NBKT];
        int tid = threadIdx.x, b = blockIdx.x - GEMM_BLOCKS;
        if (tid < NBKT) bins[tid] = 0;
        __syncthreads();
        int e0 = b * CHUNK;
        for (int e = e0 + tid; e < e0 + CHUNK; e += 256)
            atomicAdd(&bins[dst_[e] >> 8], 1);
        __syncthreads();
        if (tid < NBKT) cnt[b * NBKT + tid] = bins[tid];
        return;
    }

    __shared__ unsigned short xb[64][136];   // x tile, bf16, +8 pad (bank spread)
    __shared__ unsigned short wb[64][136];   // W transposed: wb[col][k], bf16
    __shared__ float asl[64], adl[64];
    __shared__ float wm[4];

    int tid = threadIdx.x;
    int row0 = blockIdx.x * 64;
    if (tid < 64) { asl[tid] = a_src[tid]; adl[tid] = a_dst[tid]; }

    // stage x tile: 64 rows x 128 f32 -> bf16 (coalesced float4 reads)
    #pragma unroll
    for (int it = 0; it < 8; ++it) {
        int idx = tid + it * 256;        // 0..2047
        int r = idx >> 5;                // row 0..63
        int kq = idx & 31;               // float4 index within row (128/4)
        int grow = row0 + r;
        float4 v = (grow < n) ? ((const float4*)x)[(size_t)grow * 32 + kq]
                              : make_float4(0.f, 0.f, 0.f, 0.f);
        xb[r][kq * 4 + 0] = f2bf_bits(v.x);
        xb[r][kq * 4 + 1] = f2bf_bits(v.y);
        xb[r][kq * 4 + 2] = f2bf_bits(v.z);
        xb[r][kq * 4 + 3] = f2bf_bits(v.w);
    }
    // stage W transposed: W[k][c] f32 -> wb[c][k] bf16
    #pragma unroll
    for (int it = 0; it < 8; ++it) {
        int idx = tid + it * 256;        // 0..2047 (128*64/4)
        int k  = idx >> 4;               // 0..127
        int cq = idx & 15;               // col quad
        float4 v = ((const float4*)W)[idx];
        wb[cq * 4 + 0][k] = f2bf_bits(v.x);
        wb[cq * 4 + 1][k] = f2bf_bits(v.y);
        wb[cq * 4 + 2][k] = f2bf_bits(v.z);
        wb[cq * 4 + 3][k] = f2bf_bits(v.w);
    }
    __syncthreads();

    int wv = tid >> 6, l = tid & 63;
    int rsub = l & 15;                   // A-row / B-col within tile
    int kg = l >> 4;                     // k-group

    f32x4 acc0 = (f32x4)0.f, acc1 = (f32x4)0.f, acc2c = (f32x4)0.f, acc3 = (f32x4)0.f;
    #pragma unroll
    for (int ks = 0; ks < 4; ++ks) {
        int kb = ks * 32 + kg * 8;
        short8v a = *(const short8v*)&xb[wv * 16 + rsub][kb];
        short8v b0 = *(const short8v*)&wb[ 0 + rsub][kb];
        short8v b1 = *(const short8v*)&wb[16 + rsub][kb];
        short8v b2 = *(const short8v*)&wb[32 + rsub][kb];
        short8v b3 = *(const short8v*)&wb[48 + rsub][kb];
        acc0  = __builtin_amdgcn_mfma_f32_16x16x32_bf16(a, b0, acc0,  0, 0, 0);
        acc1  = __builtin_amdgcn_mfma_f32_16x16x32_bf16(a, b1, acc1,  0, 0, 0);
        acc2c = __builtin_amdgcn_mfma_f32_16x16x32_bf16(a, b2, acc2c, 0, 0, 0);
        acc3  = __builtin_amdgcn_mfma_f32_16x16x32_bf16(a, b3, acc3,  0, 0, 0);
    }

    // epilogue: lane holds rows (kg*4 + r), cols (rsub + 16c)
    float wmax = -INFINITY;
    #pragma unroll
    for (int r = 0; r < 4; ++r) {
        int grow = row0 + wv * 16 + kg * 4 + r;
        float v0 = acc0[r], v1 = acc1[r], v2 = acc2c[r], v3 = acc3[r];
        if (grow < n) {
            h[(size_t)grow * 64 + rsub +  0] = __float2half(v0);
            h[(size_t)grow * 64 + rsub + 16] = __float2half(v1);
            h[(size_t)grow * 64 + rsub + 32] = __float2half(v2);
            h[(size_t)grow * 64 + rsub + 48] = __float2half(v3);
        }
        float s1 = v0 * asl[rsub] + v1 * asl[rsub + 16] + v2 * asl[rsub + 32] + v3 * asl[rsub + 48];
        float s2 = v0 * adl[rsub] + v1 * adl[rsub + 16] + v2 * adl[rsub + 32] + v3 * adl[rsub + 48];
        #pragma unroll
        for (int mk = 1; mk < 16; mk <<= 1) {
            s1 += __shfl_xor(s1, mk, 64);
            s2 += __shfl_xor(s2, mk, 64);
        }
        if (grow < n) {
            if (rsub == 0) { s_src[grow] = s1; s_dst[grow] = s2; }
            wmax = fmaxf(wmax, s1);      // s1 uniform across the 16-lane group
        }
    }
    wmax = fmaxf(wmax, __shfl_xor(wmax, 16, 64));
    wmax = fmaxf(wmax, __shfl_xor(wmax, 32, 64));
    if (l == 0) wm[wv] = wmax;
    __syncthreads();
    if (tid == 0)
        bmax[blockIdx.x] = fmaxf(fmaxf(wm[0], wm[1]), fmaxf(wm[2], wm[3]));
}

// ---------------------------------------------------------------------------
// gemm2 (VALU, fp16 input) — R18-identical gemm_body, XT = __half only.
// ---------------------------------------------------------------------------
template <int K>
__global__ __launch_bounds__(256) void gat_gemm_kernel_h(
    const __half* __restrict__ x, const float* __restrict__ W,
    const float* __restrict__ a_src, const float* __restrict__ a_dst,
    __half* __restrict__ h, float* __restrict__ s_src, float* __restrict__ s_dst,
    unsigned* __restrict__ gmax_enc, int n)
{
    constexpr int BK = 32;
    __shared__ float Wl[BK][64];
    __shared__ float xt[BK][68];
    __shared__ float asl[64], adl[64];
    __shared__ float wm[4];

    int tid = threadIdx.x;
    if (tid < 64) { asl[tid] = a_src[tid]; adl[tid] = a_dst[tid]; }
    int tx = tid & 15, ty = tid >> 4;
    int row0 = blockIdx.x * 64;

    float acc[4][4] = {};

    for (int k0 = 0; k0 < K; k0 += BK) {
        __syncthreads();
        {
            const float4* Wg = (const float4*)&W[(size_t)k0 * 64];
            float4* Ws = (float4*)&Wl[0][0];
            Ws[tid]       = Wg[tid];
            Ws[tid + 256] = Wg[tid + 256];
        }
        #pragma unroll
        for (int it = 0; it < 2; ++it) {
            int idx = tid + it * 256;
            int r = idx >> 3, kq = idx & 7;
            int grow = row0 + r;
            float4 v;
            if (grow < n) {
                uint2 raw = *(const uint2*)&x[(size_t)grow * K + k0 + kq * 4];
                float2 lo = __half22float2(*(__half2*)&raw.x);
                float2 hi = __half22float2(*(__half2*)&raw.y);
                v = make_float4(lo.x, lo.y, hi.x, hi.y);
            } else {
                v = make_float4(0.f, 0.f, 0.f, 0.f);
            }
            xt[kq * 4 + 0][r] = v.x;
            xt[kq * 4 + 1][r] = v.y;
            xt[kq * 4 + 2][r] = v.z;
            xt[kq * 4 + 3][r] = v.w;
        }
        __syncthreads();

        #pragma unroll
        for (int kk = 0; kk < BK; ++kk) {
            float4 wv = *(const float4*)&Wl[kk][tx * 4];
            float4 xv = *(const float4*)&xt[kk][ty * 4];
            acc[0][0] += xv.x * wv.x; acc[0][1] += xv.x * wv.y; acc[0][2] += xv.x * wv.z; acc[0][3] += xv.x * wv.w;
            acc[1][0] += xv.y * wv.x; acc[1][1] += xv.y * wv.y; acc[1][2] += xv.y * wv.z; acc[1][3] += xv.y * wv.w;
            acc[2][0] += xv.z * wv.x; acc[2][1] += xv.z * wv.y; acc[2][2] += xv.z * wv.z; acc[2][3] += xv.z * wv.w;
            acc[3][0] += xv.w * wv.x; acc[3][1] += xv.w * wv.y; acc[3][2] += xv.w * wv.z; acc[3][3] += xv.w * wv.w;
        }
    }

    float wmax = -INFINITY;
    #pragma unroll
    for (int i = 0; i < 4; ++i) {
        int grow = row0 + ty * 4 + i;
        if (grow < n) {
            __half2 p0 = __floats2half2_rn(acc[i][0], acc[i][1]);
            __half2 p1 = __floats2half2_rn(acc[i][2], acc[i][3]);
            uint2 pk = make_uint2(*(unsigned*)&p0, *(unsigned*)&p1);
            *(uint2*)&h[(size_t)grow * 64 + tx * 4] = pk;
        }
        float s1 = acc[i][0] * asl[tx*4+0] + acc[i][1] * asl[tx*4+1]
                 + acc[i][2] * asl[tx*4+2] + acc[i][3] * asl[tx*4+3];
        float s2 = acc[i][0] * adl[tx*4+0] + acc[i][1] * adl[tx*4+1]
                 + acc[i][2] * adl[tx*4+2] + acc[i][3] * adl[tx*4+3];
        #pragma unroll
        for (int m = 1; m < 16; m <<= 1) {
            s1 += __shfl_xor(s1, m, 64);
            s2 += __shfl_xor(s2, m, 64);
        }
        if (grow < n) wmax = fmaxf(wmax, s1);
        if (tx == 0 && grow < n) { s_src[grow] = s1; s_dst[grow] = s2; }
    }
    wmax = fmaxf(wmax, __shfl_xor(wmax, 16, 64));
    wmax = fmaxf(wmax, __shfl_xor(wmax, 32, 64));
    if ((tid & 63) == 0) wm[tid >> 6] = wmax;
    __syncthreads();
    if (tid == 0) {
        float bm = fmaxf(fmaxf(wm[0], wm[1]), fmaxf(wm[2], wm[3]));
        atomicMax(gmax_enc, enc_f(bm));   // 782 blocks: cheap
    }
}

// ---------------------------------------------------------------------------
// K2: P2+P3 fused, barrier-free. Block 0 also writes btot, reduces
// bmax -> gmaxu[0], zeroes gmaxu[1].
// ---------------------------------------------------------------------------
__global__ __launch_bounds__(256) void p23_fused(
    const int* __restrict__ cnt, int* __restrict__ btot,
    const float* __restrict__ bmax, unsigned* __restrict__ gmaxu,
    const int* __restrict__ src, const int* __restrict__ dst,
    unsigned* __restrict__ bkted)
{
    __shared__ int tmp[256];
    __shared__ int boffL[NBKT];
    __shared__ float fm[4];
    int b = blockIdx.x, tid = threadIdx.x;

    int total = 0, myoff = 0;
    if (tid < NBKT) {
        for (int bp = 0; bp < EBLK; ++bp) {
            int v = cnt[bp * NBKT + tid];
            total += v;
            if (bp < b) myoff += v;
        }
    }
    tmp[tid] = (tid < NBKT) ? total : 0;
    __syncthreads();
    for (int off = 1; off < 256; off <<= 1) {
        int a = (tid >= off) ? tmp[tid - off] : 0;
        __syncthreads();
        tmp[tid] += a;
        __syncthreads();
    }
    if (tid < NBKT) {
        int base = tmp[tid] - total;
        boffL[tid] = base + myoff;
        if (b == 0) btot[tid] = total;
    }
    __syncthreads();

    int e0 = b * CHUNK;
    for (int e = e0 + tid; e < e0 + CHUNK; e += 256) {
        int d = dst[e], s = src[e];
        int pos = atomicAdd(&boffL[d >> 8], 1);
        bkted[pos] = ((unsigned)(d & 255) << 16) | (unsigned)s;
    }

    if (b == 0) {
        float m = -INFINITY;
        for (int i = tid; i < GEMM_BLOCKS; i += 256) m = fmaxf(m, bmax[i]);
        #pragma unroll
        for (int off = 32; off; off >>= 1) m = fmaxf(m, __shfl_xor(m, off, 64));
        if ((tid & 63) == 0) fm[tid >> 6] = m;
        __syncthreads();
        if (tid == 0) {
            gmaxu[0] = enc_f(fmaxf(fmaxf(fm[0], fm[1]), fmaxf(fm[2], fm[3])));
            gmaxu[1] = 0;
        }
    }
}

// P4: one block per bucket; per-node count/scan/scatter in LDS.
__global__ __launch_bounds__(256) void p4_csr(
    const unsigned* __restrict__ bkted, const int* __restrict__ btot,
    int* __restrict__ row_off, int* __restrict__ csr_src)
{
    __shared__ int tmp[256];
    __shared__ int cur[256];
    __shared__ int s_beg, s_end;
    int j = blockIdx.x, tid = threadIdx.x;
    int v = (tid < NBKT) ? btot[tid] : 0;
    tmp[tid] = v; __syncthreads();
    for (int off = 1; off < 256; off <<= 1) {
        int a = (tid >= off) ? tmp[tid - off] : 0;
        __syncthreads();
        tmp[tid] += a;
        __syncthreads();
    }
    if (tid == j) { s_beg = tmp[tid] - v; s_end = tmp[tid]; }
    cur[tid] = 0;
    __syncthreads();
    int beg = s_beg, end = s_end;

    for (int e = beg + tid; e < end; e += 256)
        atomicAdd(&cur[bkted[e] >> 16], 1);
    __syncthreads();
    int c = cur[tid];
    tmp[tid] = c; __syncthreads();
    for (int off = 1; off < 256; off <<= 1) {
        int a = (tid >= off) ? tmp[tid - off] : 0;
        __syncthreads();
        tmp[tid] += a;
        __syncthreads();
    }
    int offx = tmp[tid] - c;
    int node = j * 256 + tid;
    if (node < N_NODES) row_off[node] = beg + offx;
    if (node == 0) row_off[N_NODES] = N_EDGES;
    __syncthreads();
    cur[tid] = offx;
    __syncthreads();
    for (int e = beg + tid; e < end; e += 256) {
        unsigned u = bkted[e];
        int pos = beg + atomicAdd(&cur[u >> 16], 1);
        csr_src[pos] = (int)(u & 0xFFFFu);
    }
}

// ---------------------------------------------------------------------------
// Fused per-node attention kernel (R18-identical). OT = __half (layer 1,
// fp16 scratch out) or float (layer 2, d_out).
// ---------------------------------------------------------------------------
template <bool RELU, typename OT>
__global__ __launch_bounds__(256) void gat_node_kernel(
    const int* __restrict__ row_off, const int* __restrict__ csr_src,
    const float* __restrict__ s_src, const float* __restrict__ s_dst,
    const __half* __restrict__ h, const float* __restrict__ b,
    const unsigned* __restrict__ gmax_enc, OT* __restrict__ out, int n)
{
    int row = blockIdx.x * 4 + (threadIdx.x >> 6);
    int lane = threadIdx.x & 63;
    if (row >= n) return;

    int beg = row_off[row], end = row_off[row + 1];
    int deg = end - beg;
    float sd = s_dst[row];
    float m = leaky(dec_f(*gmax_enc) + sd);
    float s_self = s_src[row];
    float hself = __half2float(h[(size_t)row * 64 + lane]);
    float wself = __expf(leaky(s_self + sd) - m);

    float v;
    if (deg <= 32) {
        int mysrc = row;
        if (lane < deg) mysrc = csr_src[beg + lane];
        float my_s = s_src[mysrc];
        float mylogit = (lane < deg) ? leaky(my_s + sd) : -INFINITY;
        float w64 = __expf(mylogit - m);
        float den = w64;
        #pragma unroll
        for (int off = 32; off; off >>= 1)
            den += __shfl_xor(den, off, 64);
        den += wself;

        float acc = wself * hself;
        if (deg <= 16) acc = salvo<16>(mysrc, w64, h, lane, acc);
        else           acc = salvo<32>(mysrc, w64, h, lane, acc);
        v = acc / den + b[lane];
    } else {
        int   mysrc   = row;
        float mylogit = -INFINITY;
        if (lane < deg) {
            mysrc = csr_src[beg + lane];
            mylogit = leaky(s_src[mysrc] + sd);
        }
        float w64 = __expf(mylogit - m);
        float den = w64;
        #pragma unroll
        for (int off = 32; off; off >>= 1)
            den += __shfl_xor(den, off, 64);
        den += wself;

        float acc = wself * hself;
        int d0 = deg < 64 ? deg : 64;
        int nb = (d0 + 15) & ~15;
        for (int i = 0; i < nb; i += 16) {
            float hv[16];
            #pragma unroll
            for (int j = 0; j < 16; ++j) {
                int s = __builtin_amdgcn_readlane(mysrc, i + j);
                hv[j] = __half2float(h[(size_t)s * 64 + lane]);
            }
            #pragma unroll
            for (int j = 0; j < 16; ++j)
                acc += readlane_f(w64, i + j) * hv[j];
        }
        for (int e = beg + 64; e < end; ++e) {
            int s = csr_src[e];
            float w = __expf(leaky(s_src[s] + sd) - m);
            den += w;
            acc += w * __half2float(h[(size_t)s * 64 + lane]);
        }
        v = acc / den + b[lane];
    }

    if (RELU) v = fmaxf(v, 0.f);
    if constexpr (std::is_same<OT, __half>::value)
        out[(size_t)row * 64 + lane] = __float2half(v);
    else
        out[(size_t)row * 64 + lane] = v;
}

// ---------------------------------------------------------------------------
extern "C" void kernel_launch(void* const* d_in, const int* in_sizes, int n_in,
                              void* d_out, int out_size, void* d_ws, size_t ws_size,
                              hipStream_t stream) {
    const float* x   = (const float*)d_in[0];
    const int*   ei  = (const int*)d_in[1];
    const float* W1  = (const float*)d_in[2];
    const float* a1s = (const float*)d_in[3];
    const float* a1d = (const float*)d_in[4];
    const float* b1  = (const float*)d_in[5];
    const float* W2  = (const float*)d_in[6];
    const float* a2s = (const float*)d_in[7];
    const float* a2d = (const float*)d_in[8];
    const float* b2  = (const float*)d_in[9];
    float* out = (float*)d_out;

    const int* src = ei;
    const int* dst = ei + N_EDGES;

    char* p = (char*)d_ws;
    __half* h    = (__half*)p;          p += (size_t)N_NODES * 64 * 2;
    __half* outh = (__half*)p;          p += (size_t)N_NODES * 64 * 2;  // fp16 layer-1 out
    float* ssrc = (float*)p;            p += (size_t)N_NODES * 4;
    float* sdst = (float*)p;            p += (size_t)N_NODES * 4;
    int* row_off = (int*)p;             p += (size_t)(N_NODES + 1) * 4;
    unsigned* gmaxu = (unsigned*)p;     p += 4 * 4;   // [gmax1, gmax2]
    float* bmax = (float*)p;            p += 1024 * 4;
    int* csr_src = (int*)p;             p += (size_t)N_EDGES * 4;
    int* cnt     = (int*)p;             p += (size_t)EBLK * NBKT * 4;
    int* btot    = (int*)p;             p += (size_t)NBKT * 4;
    unsigned* bkted = (unsigned*)p;     p += (size_t)N_EDGES * 4;  // own buffer (h live)

    dim3 blk(256);
    int node_blocks = (N_NODES + 3) / 4;

    // K1: MFMA gemm1 (bf16(x)@bf16(W1) -> h fp16, scores, bmax) || CSR P1
    fused_gemm1_p1<<<GEMM_BLOCKS + EBLK, blk, 0, stream>>>(
        x, W1, a1s, a1d, h, ssrc, sdst, bmax, dst, cnt, N_NODES);
    // K2: CSR P2+P3 fused (redundant scans, no barrier) + gmax1 reduce
    p23_fused<<<EBLK, blk, 0, stream>>>(cnt, btot, bmax, gmaxu, src, dst, bkted);
    // K3: CSR P4
    p4_csr<<<NBKT, blk, 0, stream>>>(bkted, btot, row_off, csr_src);
    // K4: layer-1 aggregation -> fp16 scratch
    gat_node_kernel<true, __half><<<node_blocks, blk, 0, stream>>>(
        row_off, csr_src, ssrc, sdst, h, b1, gmaxu + 0, outh, N_NODES);
    // K5: gemm2 (fp16 input, VALU)
    gat_gemm_kernel_h<64><<<GEMM_BLOCKS, blk, 0, stream>>>(
        outh, W2, a2s, a2d, h, ssrc, sdst, gmaxu + 1, N_NODES);
    // K6: layer-2 aggregation -> d_out
    gat_node_kernel<false, float><<<node_blocks, blk, 0, stream>>>(
        row_off, csr_src, ssrc, sdst, h, b2, gmaxu + 1, out, N_NODES);
}

// Round 20
// 112.175 us; speedup vs baseline: 2.0483x; 1.0388x over previous
//
#include <hip/hip_runtime.h>
#include <hip/hip_fp16.h>
#include <type_traits>

#define N_NODES 50000
#define N_EDGES 800000
#define NEG_SLOPE 0.2f
#define NBKT 196            // ceil(50000/256) buckets of 256 nodes
#define EBLK 200            // edge blocks
#define CHUNK 4000          // edges per block (EBLK*CHUNK == N_EDGES)
#define GEMM_BLOCKS 782     // ceil(50000/64)

typedef __attribute__((ext_vector_type(8))) short short8v;      // 8 bf16
typedef __attribute__((ext_vector_type(8))) _Float16 half8v;    // 8 fp16
typedef __attribute__((ext_vector_type(4))) float f32x4;        // MFMA acc

__device__ __forceinline__ float leaky(float x) { return x >= 0.f ? x : NEG_SLOPE * x; }
__device__ __forceinline__ float readlane_f(float v, int i) {
    return __uint_as_float(__builtin_amdgcn_readlane(__float_as_uint(v), i));
}
// order-preserving float<->uint mapping for atomicMax on mixed-sign floats
__device__ __forceinline__ unsigned enc_f(float f) {
    unsigned u = __float_as_uint(f);
    return (int)u < 0 ? ~u : (u | 0x80000000u);
}
__device__ __forceinline__ float dec_f(unsigned e) {
    return __uint_as_float((int)e < 0 ? (e & 0x7FFFFFFFu) : ~e);
}
// f32 -> bf16 bits, round-to-nearest-even
__device__ __forceinline__ unsigned short f2bf_bits(float f) {
    unsigned u = __float_as_uint(f);
    unsigned r = u + 0x7FFFu + ((u >> 16) & 1u);
    return (unsigned short)(r >> 16);
}

// NL-deep pipelined gather salvo (NL >= wave's deg; fillers carry w=0 and
// hit the L1-hot self row)
template <int NL>
__device__ __forceinline__ float salvo(int mysrc, float w64,
                                       const __half* __restrict__ h,
                                       int lane, float acc)
{
    float hv[NL];
    #pragma unroll
    for (int j = 0; j < NL; ++j) {
        int s = __builtin_amdgcn_readlane(mysrc, j);
        hv[j] = __half2float(h[(size_t)s * 64 + lane]);
    }
    #pragma unroll
    for (int j = 0; j < NL; ++j)
        acc += readlane_f(w64, j) * hv[j];
    return acc;
}

// ---------------------------------------------------------------------------
// Shared MFMA epilogue: lane holds rows (kg*4+r) of cols (rsub+16c).
// Writes h fp16, s-scores (16-lane shfl reduce), block max via wm.
// ---------------------------------------------------------------------------
__device__ __forceinline__ void mfma_epilogue(
    f32x4 acc0, f32x4 acc1, f32x4 acc2c, f32x4 acc3,
    int row0, int wv, int rsub, int kg, int n,
    const float* asl, const float* adl, float* wm,
    __half* __restrict__ h, float* __restrict__ s_src, float* __restrict__ s_dst)
{
    float wmax = -INFINITY;
    #pragma unroll
    for (int r = 0; r < 4; ++r) {
        int grow = row0 + wv * 16 + kg * 4 + r;
        float v0 = acc0[r], v1 = acc1[r], v2 = acc2c[r], v3 = acc3[r];
        if (grow < n) {
            h[(size_t)grow * 64 + rsub +  0] = __float2half(v0);
            h[(size_t)grow * 64 + rsub + 16] = __float2half(v1);
            h[(size_t)grow * 64 + rsub + 32] = __float2half(v2);
            h[(size_t)grow * 64 + rsub + 48] = __float2half(v3);
        }
        float s1 = v0 * asl[rsub] + v1 * asl[rsub + 16] + v2 * asl[rsub + 32] + v3 * asl[rsub + 48];
        float s2 = v0 * adl[rsub] + v1 * adl[rsub + 16] + v2 * adl[rsub + 32] + v3 * adl[rsub + 48];
        #pragma unroll
        for (int mk = 1; mk < 16; mk <<= 1) {
            s1 += __shfl_xor(s1, mk, 64);
            s2 += __shfl_xor(s2, mk, 64);
        }
        if (grow < n) {
            if (rsub == 0) { s_src[grow] = s1; s_dst[grow] = s2; }
            wmax = fmaxf(wmax, s1);
        }
    }
    wmax = fmaxf(wmax, __shfl_xor(wmax, 16, 64));
    wmax = fmaxf(wmax, __shfl_xor(wmax, 32, 64));
    int l = rsub + kg * 16;
    if (l == 0) wm[wv] = wmax;
}

// ---------------------------------------------------------------------------
// K1: MFMA gemm1 (blocks 0..781) || CSR P1 histogram (blocks 782..981).
// h(fp16) = bf16(x) @ bf16(W1), f32 accumulate, 16x16x32_bf16. 64x64 tile,
// K=128 in 4 steps.
// ---------------------------------------------------------------------------
__global__ __launch_bounds__(256) void fused_gemm1_p1(
    const float* __restrict__ x, const float* __restrict__ W,
    const float* __restrict__ a_src, const float* __restrict__ a_dst,
    __half* __restrict__ h, float* __restrict__ s_src, float* __restrict__ s_dst,
    float* __restrict__ bmax,
    const int* __restrict__ dst_, int* __restrict__ cnt, int n)
{
    if (blockIdx.x >= GEMM_BLOCKS) {
        __shared__ int bins[NBKT];
        int tid = threadIdx.x, b = blockIdx.x - GEMM_BLOCKS;
        if (tid < NBKT) bins[tid] = 0;
        __syncthreads();
        int e0 = b * CHUNK;
        for (int e = e0 + tid; e < e0 + CHUNK; e += 256)
            atomicAdd(&bins[dst_[e] >> 8], 1);
        __syncthreads();
        if (tid < NBKT) cnt[b * NBKT + tid] = bins[tid];
        return;
    }

    __shared__ unsigned short xb[64][136];
    __shared__ unsigned short wb[64][136];
    __shared__ float asl[64], adl[64];
    __shared__ float wm[4];

    int tid = threadIdx.x;
    int row0 = blockIdx.x * 64;
    if (tid < 64) { asl[tid] = a_src[tid]; adl[tid] = a_dst[tid]; }

    #pragma unroll
    for (int it = 0; it < 8; ++it) {
        int idx = tid + it * 256;
        int r = idx >> 5, kq = idx & 31;
        int grow = row0 + r;
        float4 v = (grow < n) ? ((const float4*)x)[(size_t)grow * 32 + kq]
                              : make_float4(0.f, 0.f, 0.f, 0.f);
        xb[r][kq * 4 + 0] = f2bf_bits(v.x);
        xb[r][kq * 4 + 1] = f2bf_bits(v.y);
        xb[r][kq * 4 + 2] = f2bf_bits(v.z);
        xb[r][kq * 4 + 3] = f2bf_bits(v.w);
    }
    #pragma unroll
    for (int it = 0; it < 8; ++it) {
        int idx = tid + it * 256;
        int k = idx >> 4, cq = idx & 15;
        float4 v = ((const float4*)W)[idx];
        wb[cq * 4 + 0][k] = f2bf_bits(v.x);
        wb[cq * 4 + 1][k] = f2bf_bits(v.y);
        wb[cq * 4 + 2][k] = f2bf_bits(v.z);
        wb[cq * 4 + 3][k] = f2bf_bits(v.w);
    }
    __syncthreads();

    int wv = tid >> 6, l = tid & 63;
    int rsub = l & 15, kg = l >> 4;

    f32x4 acc0 = (f32x4)0.f, acc1 = (f32x4)0.f, acc2c = (f32x4)0.f, acc3 = (f32x4)0.f;
    #pragma unroll
    for (int ks = 0; ks < 4; ++ks) {
        int kb = ks * 32 + kg * 8;
        short8v a = *(const short8v*)&xb[wv * 16 + rsub][kb];
        short8v b0 = *(const short8v*)&wb[ 0 + rsub][kb];
        short8v b1 = *(const short8v*)&wb[16 + rsub][kb];
        short8v b2 = *(const short8v*)&wb[32 + rsub][kb];
        short8v b3 = *(const short8v*)&wb[48 + rsub][kb];
        acc0  = __builtin_amdgcn_mfma_f32_16x16x32_bf16(a, b0, acc0,  0, 0, 0);
        acc1  = __builtin_amdgcn_mfma_f32_16x16x32_bf16(a, b1, acc1,  0, 0, 0);
        acc2c = __builtin_amdgcn_mfma_f32_16x16x32_bf16(a, b2, acc2c, 0, 0, 0);
        acc3  = __builtin_amdgcn_mfma_f32_16x16x32_bf16(a, b3, acc3,  0, 0, 0);
    }

    mfma_epilogue(acc0, acc1, acc2c, acc3, row0, wv, rsub, kg, n,
                  asl, adl, wm, h, s_src, s_dst);
    __syncthreads();
    if (tid == 0)
        bmax[blockIdx.x] = fmaxf(fmaxf(wm[0], wm[1]), fmaxf(wm[2], wm[3]));
}

// ---------------------------------------------------------------------------
// K5: MFMA gemm2. h(fp16) = fp16(outh) @ f16(W2), 16x16x32_f16, K=64 in
// 2 steps. Input already fp16 -> zero-conversion A staging.
// ---------------------------------------------------------------------------
__global__ __launch_bounds__(256) void gemm2_mfma(
    const __half* __restrict__ x, const float* __restrict__ W,
    const float* __restrict__ a_src, const float* __restrict__ a_dst,
    __half* __restrict__ h, float* __restrict__ s_src, float* __restrict__ s_dst,
    unsigned* __restrict__ gmax_enc, int n)
{
    __shared__ _Float16 xb[64][72];     // x tile fp16, +8 pad
    __shared__ _Float16 wb[64][72];     // W transposed f16: wb[col][k]
    __shared__ float asl[64], adl[64];
    __shared__ float wm[4];

    int tid = threadIdx.x;
    int row0 = blockIdx.x * 64;
    if (tid < 64) { asl[tid] = a_src[tid]; adl[tid] = a_dst[tid]; }

    // stage x tile: 64 rows x 64 fp16 (uint4 = 8 halves, direct copy)
    #pragma unroll
    for (int it = 0; it < 2; ++it) {
        int idx = tid + it * 256;       // 0..511
        int r = idx >> 3, q = idx & 7;
        int grow = row0 + r;
        uint4 v = (grow < n) ? *(const uint4*)&x[(size_t)grow * 64 + q * 8]
                             : make_uint4(0u, 0u, 0u, 0u);
        *(uint4*)&xb[r][q * 8] = v;
    }
    // stage W transposed: W[k][c] f32 -> wb[c][k] f16
    #pragma unroll
    for (int it = 0; it < 4; ++it) {
        int idx = tid + it * 256;       // 0..1023
        int k = idx >> 4, cq = idx & 15;
        float4 v = ((const float4*)W)[idx];
        wb[cq * 4 + 0][k] = (_Float16)v.x;
        wb[cq * 4 + 1][k] = (_Float16)v.y;
        wb[cq * 4 + 2][k] = (_Float16)v.z;
        wb[cq * 4 + 3][k] = (_Float16)v.w;
    }
    __syncthreads();

    int wv = tid >> 6, l = tid & 63;
    int rsub = l & 15, kg = l >> 4;

    f32x4 acc0 = (f32x4)0.f, acc1 = (f32x4)0.f, acc2c = (f32x4)0.f, acc3 = (f32x4)0.f;
    #pragma unroll
    for (int ks = 0; ks < 2; ++ks) {
        int kb = ks * 32 + kg * 8;
        half8v a = *(const half8v*)&xb[wv * 16 + rsub][kb];
        half8v b0 = *(const half8v*)&wb[ 0 + rsub][kb];
        half8v b1 = *(const half8v*)&wb[16 + rsub][kb];
        half8v b2 = *(const half8v*)&wb[32 + rsub][kb];
        half8v b3 = *(const half8v*)&wb[48 + rsub][kb];
        acc0  = __builtin_amdgcn_mfma_f32_16x16x32_f16(a, b0, acc0,  0, 0, 0);
        acc1  = __builtin_amdgcn_mfma_f32_16x16x32_f16(a, b1, acc1,  0, 0, 0);
        acc2c = __builtin_amdgcn_mfma_f32_16x16x32_f16(a, b2, acc2c, 0, 0, 0);
        acc3  = __builtin_amdgcn_mfma_f32_16x16x32_f16(a, b3, acc3,  0, 0, 0);
    }

    mfma_epilogue(acc0, acc1, acc2c, acc3, row0, wv, rsub, kg, n,
                  asl, adl, wm, h, s_src, s_dst);
    __syncthreads();
    if (tid == 0) {
        float bm = fmaxf(fmaxf(wm[0], wm[1]), fmaxf(wm[2], wm[3]));
        atomicMax(gmax_enc, enc_f(bm));   // 782 blocks: cheap
    }
}

// ---------------------------------------------------------------------------
// K2: P2+P3 fused, barrier-free. Block 0 also writes btot, reduces
// bmax -> gmaxu[0], zeroes gmaxu[1].
// ---------------------------------------------------------------------------
__global__ __launch_bounds__(256) void p23_fused(
    const int* __restrict__ cnt, int* __restrict__ btot,
    const float* __restrict__ bmax, unsigned* __restrict__ gmaxu,
    const int* __restrict__ src, const int* __restrict__ dst,
    unsigned* __restrict__ bkted)
{
    __shared__ int tmp[256];
    __shared__ int boffL[NBKT];
    __shared__ float fm[4];
    int b = blockIdx.x, tid = threadIdx.x;

    int total = 0, myoff = 0;
    if (tid < NBKT) {
        for (int bp = 0; bp < EBLK; ++bp) {
            int v = cnt[bp * NBKT + tid];
            total += v;
            if (bp < b) myoff += v;
        }
    }
    tmp[tid] = (tid < NBKT) ? total : 0;
    __syncthreads();
    for (int off = 1; off < 256; off <<= 1) {
        int a = (tid >= off) ? tmp[tid - off] : 0;
        __syncthreads();
        tmp[tid] += a;
        __syncthreads();
    }
    if (tid < NBKT) {
        int base = tmp[tid] - total;
        boffL[tid] = base + myoff;
        if (b == 0) btot[tid] = total;
    }
    __syncthreads();

    int e0 = b * CHUNK;
    for (int e = e0 + tid; e < e0 + CHUNK; e += 256) {
        int d = dst[e], s = src[e];
        int pos = atomicAdd(&boffL[d >> 8], 1);
        bkted[pos] = ((unsigned)(d & 255) << 16) | (unsigned)s;
    }

    if (b == 0) {
        float m = -INFINITY;
        for (int i = tid; i < GEMM_BLOCKS; i += 256) m = fmaxf(m, bmax[i]);
        #pragma unroll
        for (int off = 32; off; off >>= 1) m = fmaxf(m, __shfl_xor(m, off, 64));
        if ((tid & 63) == 0) fm[tid >> 6] = m;
        __syncthreads();
        if (tid == 0) {
            gmaxu[0] = enc_f(fmaxf(fmaxf(fm[0], fm[1]), fmaxf(fm[2], fm[3])));
            gmaxu[1] = 0;
        }
    }
}

// P4: one block per bucket; per-node count/scan/scatter in LDS.
__global__ __launch_bounds__(256) void p4_csr(
    const unsigned* __restrict__ bkted, const int* __restrict__ btot,
    int* __restrict__ row_off, int* __restrict__ csr_src)
{
    __shared__ int tmp[256];
    __shared__ int cur[256];
    __shared__ int s_beg, s_end;
    int j = blockIdx.x, tid = threadIdx.x;
    int v = (tid < NBKT) ? btot[tid] : 0;
    tmp[tid] = v; __syncthreads();
    for (int off = 1; off < 256; off <<= 1) {
        int a = (tid >= off) ? tmp[tid - off] : 0;
        __syncthreads();
        tmp[tid] += a;
        __syncthreads();
    }
    if (tid == j) { s_beg = tmp[tid] - v; s_end = tmp[tid]; }
    cur[tid] = 0;
    __syncthreads();
    int beg = s_beg, end = s_end;

    for (int e = beg + tid; e < end; e += 256)
        atomicAdd(&cur[bkted[e] >> 16], 1);
    __syncthreads();
    int c = cur[tid];
    tmp[tid] = c; __syncthreads();
    for (int off = 1; off < 256; off <<= 1) {
        int a = (tid >= off) ? tmp[tid - off] : 0;
        __syncthreads();
        tmp[tid] += a;
        __syncthreads();
    }
    int offx = tmp[tid] - c;
    int node = j * 256 + tid;
    if (node < N_NODES) row_off[node] = beg + offx;
    if (node == 0) row_off[N_NODES] = N_EDGES;
    __syncthreads();
    cur[tid] = offx;
    __syncthreads();
    for (int e = beg + tid; e < end; e += 256) {
        unsigned u = bkted[e];
        int pos = beg + atomicAdd(&cur[u >> 16], 1);
        csr_src[pos] = (int)(u & 0xFFFFu);
    }
}

// ---------------------------------------------------------------------------
// Fused per-node attention kernel (R18-identical). OT = __half (layer 1,
// fp16 scratch out) or float (layer 2, d_out).
// ---------------------------------------------------------------------------
template <bool RELU, typename OT>
__global__ __launch_bounds__(256) void gat_node_kernel(
    const int* __restrict__ row_off, const int* __restrict__ csr_src,
    const float* __restrict__ s_src, const float* __restrict__ s_dst,
    const __half* __restrict__ h, const float* __restrict__ b,
    const unsigned* __restrict__ gmax_enc, OT* __restrict__ out, int n)
{
    int row = blockIdx.x * 4 + (threadIdx.x >> 6);
    int lane = threadIdx.x & 63;
    if (row >= n) return;

    int beg = row_off[row], end = row_off[row + 1];
    int deg = end - beg;
    float sd = s_dst[row];
    float m = leaky(dec_f(*gmax_enc) + sd);
    float s_self = s_src[row];
    float hself = __half2float(h[(size_t)row * 64 + lane]);
    float wself = __expf(leaky(s_self + sd) - m);

    float v;
    if (deg <= 32) {
        int mysrc = row;
        if (lane < deg) mysrc = csr_src[beg + lane];
        float my_s = s_src[mysrc];
        float mylogit = (lane < deg) ? leaky(my_s + sd) : -INFINITY;
        float w64 = __expf(mylogit - m);
        float den = w64;
        #pragma unroll
        for (int off = 32; off; off >>= 1)
            den += __shfl_xor(den, off, 64);
        den += wself;

        float acc = wself * hself;
        if (deg <= 16) acc = salvo<16>(mysrc, w64, h, lane, acc);
        else           acc = salvo<32>(mysrc, w64, h, lane, acc);
        v = acc / den + b[lane];
    } else {
        int   mysrc   = row;
        float mylogit = -INFINITY;
        if (lane < deg) {
            mysrc = csr_src[beg + lane];
            mylogit = leaky(s_src[mysrc] + sd);
        }
        float w64 = __expf(mylogit - m);
        float den = w64;
        #pragma unroll
        for (int off = 32; off; off >>= 1)
            den += __shfl_xor(den, off, 64);
        den += wself;

        float acc = wself * hself;
        int d0 = deg < 64 ? deg : 64;
        int nb = (d0 + 15) & ~15;
        for (int i = 0; i < nb; i += 16) {
            float hv[16];
            #pragma unroll
            for (int j = 0; j < 16; ++j) {
                int s = __builtin_amdgcn_readlane(mysrc, i + j);
                hv[j] = __half2float(h[(size_t)s * 64 + lane]);
            }
            #pragma unroll
            for (int j = 0; j < 16; ++j)
                acc += readlane_f(w64, i + j) * hv[j];
        }
        for (int e = beg + 64; e < end; ++e) {
            int s = csr_src[e];
            float w = __expf(leaky(s_src[s] + sd) - m);
            den += w;
            acc += w * __half2float(h[(size_t)s * 64 + lane]);
        }
        v = acc / den + b[lane];
    }

    if (RELU) v = fmaxf(v, 0.f);
    if constexpr (std::is_same<OT, __half>::value)
        out[(size_t)row * 64 + lane] = __float2half(v);
    else
        out[(size_t)row * 64 + lane] = v;
}

// ---------------------------------------------------------------------------
extern "C" void kernel_launch(void* const* d_in, const int* in_sizes, int n_in,
                              void* d_out, int out_size, void* d_ws, size_t ws_size,
                              hipStream_t stream) {
    const float* x   = (const float*)d_in[0];
    const int*   ei  = (const int*)d_in[1];
    const float* W1  = (const float*)d_in[2];
    const float* a1s = (const float*)d_in[3];
    const float* a1d = (const float*)d_in[4];
    const float* b1  = (const float*)d_in[5];
    const float* W2  = (const float*)d_in[6];
    const float* a2s = (const float*)d_in[7];
    const float* a2d = (const float*)d_in[8];
    const float* b2  = (const float*)d_in[9];
    float* out = (float*)d_out;

    const int* src = ei;
    const int* dst = ei + N_EDGES;

    char* p = (char*)d_ws;
    __half* h    = (__half*)p;          p += (size_t)N_NODES * 64 * 2;
    __half* outh = (__half*)p;          p += (size_t)N_NODES * 64 * 2;  // fp16 layer-1 out
    float* ssrc = (float*)p;            p += (size_t)N_NODES * 4;
    float* sdst = (float*)p;            p += (size_t)N_NODES * 4;
    int* row_off = (int*)p;             p += (size_t)(N_NODES + 1) * 4;
    unsigned* gmaxu = (unsigned*)p;     p += 4 * 4;   // [gmax1, gmax2]
    float* bmax = (float*)p;            p += 1024 * 4;
    int* csr_src = (int*)p;             p += (size_t)N_EDGES * 4;
    int* cnt     = (int*)p;             p += (size_t)EBLK * NBKT * 4;
    int* btot    = (int*)p;             p += (size_t)NBKT * 4;
    unsigned* bkted = (unsigned*)p;     p += (size_t)N_EDGES * 4;  // own buffer (h live)

    dim3 blk(256);
    int node_blocks = (N_NODES + 3) / 4;

    // K1: MFMA gemm1 (bf16(x)@bf16(W1) -> h fp16, scores, bmax) || CSR P1
    fused_gemm1_p1<<<GEMM_BLOCKS + EBLK, blk, 0, stream>>>(
        x, W1, a1s, a1d, h, ssrc, sdst, bmax, dst, cnt, N_NODES);
    // K2: CSR P2+P3 fused (redundant scans, no barrier) + gmax1 reduce
    p23_fused<<<EBLK, blk, 0, stream>>>(cnt, btot, bmax, gmaxu, src, dst, bkted);
    // K3: CSR P4
    p4_csr<<<NBKT, blk, 0, stream>>>(bkted, btot, row_off, csr_src);
    // K4: layer-1 aggregation -> fp16 scratch
    gat_node_kernel<true, __half><<<node_blocks, blk, 0, stream>>>(
        row_off, csr_src, ssrc, sdst, h, b1, gmaxu + 0, outh, N_NODES);
    // K5: MFMA gemm2 (fp16 input, zero-conversion A staging)
    gemm2_mfma<<<GEMM_BLOCKS, blk, 0, stream>>>(
        outh, W2, a2s, a2d, h, ssrc, sdst, gmaxu + 1, N_NODES);
    // K6: layer-2 aggregation -> d_out
    gat_node_kernel<false, float><<<node_blocks, blk, 0, stream>>>(
        row_off, csr_src, ssrc, sdst, h, b2, gmaxu + 1, out, N_NODES);
}